// Round 3
// baseline (1840.598 us; speedup 1.0000x reference)
//
#include <hip/hip_runtime.h>
#include <hip/hip_bf16.h>
#include <math.h>

#define NNODES 100000
#define NEDGES 3200000
#define NBUK ((NNODES + 127) >> 7)   // 782 buckets of 128 nodes

// ---------------- init: zero bucket counters + small accumulators ----------------
__global__ void init_kernel(int* __restrict__ bcnt, float* __restrict__ smalls) {
    int t = threadIdx.x;
    if (t < NBUK) bcnt[t] = 0;
    if (t < 592)  smalls[t] = 0.0f;   // keys(8) colsum(8) ata(64) ge(512)
}

// ---------------- bucket histogram (LDS-aggregated) ----------------
__global__ __launch_bounds__(256) void bucket_hist_kernel(const int* __restrict__ dst,
                                                          int* __restrict__ bcnt) {
    __shared__ int h[NBUK];
    int t = threadIdx.x;
    for (int i = t; i < NBUK; i += 256) h[i] = 0;
    __syncthreads();
    int stride = gridDim.x * 256;
    for (int e = blockIdx.x * 256 + t; e < NEDGES; e += stride)
        atomicAdd(&h[dst[e] >> 7], 1);
    __syncthreads();
    for (int i = t; i < NBUK; i += 256) {
        int v = h[i];
        if (v) atomicAdd(bcnt + i, v);
    }
}

// ---------------- scan bucket counts -> starts + cursors ----------------
__global__ void bucket_scan_kernel(const int* __restrict__ bcnt, int* __restrict__ bstart,
                                   int* __restrict__ bcur, int* __restrict__ row_start) {
    __shared__ int s[1024];
    int t = threadIdx.x;
    int v = (t < NBUK) ? bcnt[t] : 0;
    s[t] = v;
    __syncthreads();
    for (int off = 1; off < 1024; off <<= 1) {
        int x = (t >= off) ? s[t - off] : 0;
        __syncthreads();
        s[t] += x;
        __syncthreads();
    }
    if (t < NBUK) {
        int ex = s[t] - v;
        bstart[t] = ex;
        bcur[t] = ex;
    }
    if (t == 0) {
        bstart[NBUK] = NEDGES;
        row_start[NNODES] = NEDGES;
    }
}

// ---------------- scatter edges into bucket regions, packed src|dloc ----------------
__global__ void bucket_scatter_kernel(const int* __restrict__ src, const int* __restrict__ dst,
                                      int* __restrict__ bcur, int* __restrict__ ebuk) {
    int e = blockIdx.x * 256 + threadIdx.x;
    if (e < NEDGES) {
        int d = dst[e];
        int pos = atomicAdd(bcur + (d >> 7), 1);
        ebuk[pos] = src[e] | ((d & 127) << 20);   // src < 2^17 fits in 20 bits
    }
}

// ---------------- per-bucket: node counts, row_start, dinv, csr fill ----------------
__global__ __launch_bounds__(256) void build_kernel(const int* __restrict__ ebuk,
                                                    const int* __restrict__ bstart,
                                                    int* __restrict__ row_start,
                                                    float* __restrict__ dinv,
                                                    int* __restrict__ csr) {
    __shared__ int cnt[128];
    __shared__ int cur[128];
    int b = blockIdx.x;
    int t = threadIdx.x;
    int s0 = bstart[b], s1 = bstart[b + 1];
    if (t < 128) cnt[t] = 0;
    __syncthreads();
    for (int i = s0 + t; i < s1; i += 256)
        atomicAdd(&cnt[(ebuk[i] >> 20) & 127], 1);
    __syncthreads();
    if (t == 0) {
        int run = s0;
        for (int i = 0; i < 128; i++) { cur[i] = run; run += cnt[i]; }
    }
    __syncthreads();
    int node = b * 128 + t;
    if (t < 128 && node < NNODES) {
        row_start[node] = cur[t];
        dinv[node] = rsqrtf((float)cnt[t] + 1.0f);
    }
    __syncthreads();
    for (int i = s0 + t; i < s1; i += 256) {
        int v = ebuk[i];
        int pos = atomicAdd(&cur[(v >> 20) & 127], 1);
        csr[pos] = v & 0xFFFFF;
    }
}

// ---------------- generic small-K GEMM: out[N,KOUT] = A[N,KIN] @ W[KIN,KOUT] ----
// optional per-row scale (dinv), bias, activation. ACT: 0 none, 1 relu, 2 tanh
template <int KIN, int KOUT, int ACT>
__global__ __launch_bounds__(256) void gemm_kernel(const float* __restrict__ A,
                                                   const float* __restrict__ W,
                                                   const float* __restrict__ bias,
                                                   const float* __restrict__ rowscale,
                                                   float* __restrict__ out, int nrows) {
    constexpr int ROWS = 1024 / KOUT;      // 256 threads * 4 outputs each
    constexpr int JG   = KOUT / 4;
    __shared__ float As[ROWS][KIN];
    int block_row = blockIdx.x * ROWS;
    int tid = threadIdx.x;

    constexpr int TOT4 = ROWS * KIN / 4;
    const float4* A4 = (const float4*)(A + (size_t)block_row * KIN);
    float4* As4 = (float4*)&As[0][0];
    for (int idx = tid; idx < TOT4; idx += 256) {
        int r = idx / (KIN / 4);
        float4 v = make_float4(0.f, 0.f, 0.f, 0.f);
        if (block_row + r < nrows) v = A4[idx];
        As4[idx] = v;
    }
    __syncthreads();

    int r = tid / JG;
    int j = (tid % JG) * 4;
    float4 acc = make_float4(0.f, 0.f, 0.f, 0.f);
    for (int k = 0; k < KIN; k++) {
        float a = As[r][k];
        float4 w = *(const float4*)(W + (size_t)k * KOUT + j);
        acc.x += a * w.x; acc.y += a * w.y; acc.z += a * w.z; acc.w += a * w.w;
    }
    if (rowscale) {
        float d = rowscale[min(block_row + r, nrows - 1)];
        acc.x *= d; acc.y *= d; acc.z *= d; acc.w *= d;
    }
    if (bias) {
        float4 b4 = *(const float4*)(bias + j);
        acc.x += b4.x; acc.y += b4.y; acc.z += b4.z; acc.w += b4.w;
    }
    if (ACT == 1) {
        acc.x = fmaxf(acc.x, 0.f); acc.y = fmaxf(acc.y, 0.f);
        acc.z = fmaxf(acc.z, 0.f); acc.w = fmaxf(acc.w, 0.f);
    } else if (ACT == 2) {
        acc.x = tanhf(acc.x); acc.y = tanhf(acc.y);
        acc.z = tanhf(acc.z); acc.w = tanhf(acc.w);
    }
    if (block_row + r < nrows)
        *(float4*)(out + (size_t)(block_row + r) * KOUT + j) = acc;
}

// ---------------- gather, K=128: one wave per node, float2 per lane ----------------
__global__ __launch_bounds__(256) void gather128_kernel(
    const float* __restrict__ hs, const int* __restrict__ row_start,
    const int* __restrict__ csr, const float* __restrict__ dinv,
    const float* __restrict__ bias, float* __restrict__ out) {
    int wave = threadIdx.x >> 6;
    int lane = threadIdx.x & 63;
    int n = blockIdx.x * 4 + wave;
    if (n >= NNODES) return;
    int start = row_start[n], end = row_start[n + 1];
    const float2* h2p = (const float2*)hs;
    size_t selfoff = (size_t)n * 64 + lane;
    float2 acc = h2p[selfoff];                    // self loop (already dinv-scaled)
    int e = start;
    for (; e + 4 <= end; e += 4) {
        int s0 = csr[e], s1 = csr[e + 1], s2 = csr[e + 2], s3 = csr[e + 3];
        float2 v0 = h2p[(size_t)s0 * 64 + lane];
        float2 v1 = h2p[(size_t)s1 * 64 + lane];
        float2 v2 = h2p[(size_t)s2 * 64 + lane];
        float2 v3 = h2p[(size_t)s3 * 64 + lane];
        acc.x += v0.x + v1.x + v2.x + v3.x;
        acc.y += v0.y + v1.y + v2.y + v3.y;
    }
    for (; e < end; e++) {
        int s = csr[e];
        float2 v = h2p[(size_t)s * 64 + lane];
        acc.x += v.x; acc.y += v.y;
    }
    float d = dinv[n];
    float2 b = ((const float2*)bias)[lane];
    acc.x = fmaxf(acc.x * d + b.x, 0.f);
    acc.y = fmaxf(acc.y * d + b.y, 0.f);
    ((float2*)out)[selfoff] = acc;
}

// ---------------- gather, K=64: one wave per node, 1 float per lane ----------------
__global__ __launch_bounds__(256) void gather64_kernel(
    const float* __restrict__ hs, const int* __restrict__ row_start,
    const int* __restrict__ csr, const float* __restrict__ dinv,
    const float* __restrict__ bias, float* __restrict__ out) {
    int wave = threadIdx.x >> 6;
    int lane = threadIdx.x & 63;
    int n = blockIdx.x * 4 + wave;
    if (n >= NNODES) return;
    int start = row_start[n], end = row_start[n + 1];
    size_t selfoff = (size_t)n * 64 + lane;
    float acc = hs[selfoff];
    int e = start;
    for (; e + 4 <= end; e += 4) {
        int s0 = csr[e], s1 = csr[e + 1], s2 = csr[e + 2], s3 = csr[e + 3];
        float v0 = hs[(size_t)s0 * 64 + lane];
        float v1 = hs[(size_t)s1 * 64 + lane];
        float v2 = hs[(size_t)s2 * 64 + lane];
        float v3 = hs[(size_t)s3 * 64 + lane];
        acc += v0 + v1 + v2 + v3;
    }
    for (; e < end; e++) acc += hs[(size_t)csr[e] * 64 + lane];
    out[selfoff] = acc * dinv[n] + bias[lane];
}

// ---------------- column max over N for 8 columns (ordered-uint atomicMax) ----------------
__global__ void colmax_kernel(const float* __restrict__ L, unsigned* __restrict__ keys) {
    float m[8];
#pragma unroll
    for (int d = 0; d < 8; d++) m[d] = -INFINITY;
    int stride = gridDim.x * blockDim.x;
    for (int i = blockIdx.x * blockDim.x + threadIdx.x; i < NNODES; i += stride) {
        float4 a = *(const float4*)(L + (size_t)i * 8);
        float4 b = *(const float4*)(L + (size_t)i * 8 + 4);
        m[0] = fmaxf(m[0], a.x); m[1] = fmaxf(m[1], a.y);
        m[2] = fmaxf(m[2], a.z); m[3] = fmaxf(m[3], a.w);
        m[4] = fmaxf(m[4], b.x); m[5] = fmaxf(m[5], b.y);
        m[6] = fmaxf(m[6], b.z); m[7] = fmaxf(m[7], b.w);
    }
#pragma unroll
    for (int off = 32; off > 0; off >>= 1)
#pragma unroll
        for (int d = 0; d < 8; d++) m[d] = fmaxf(m[d], __shfl_down(m[d], off));
    if ((threadIdx.x & 63) == 0) {
#pragma unroll
        for (int d = 0; d < 8; d++) {
            unsigned bits = __float_as_uint(m[d]);
            unsigned key = (bits & 0x80000000u) ? ~bits : (bits | 0x80000000u);
            atomicMax(keys + d, key);
        }
    }
}

// ---------------- exp(L - max) in place, column sums ----------------
__global__ void colsum_kernel(float* __restrict__ L, const unsigned* __restrict__ keys,
                              float* __restrict__ sums) {
    float mx[8];
#pragma unroll
    for (int d = 0; d < 8; d++) {
        unsigned key = keys[d];
        unsigned bits = (key & 0x80000000u) ? (key ^ 0x80000000u) : ~key;
        mx[d] = __uint_as_float(bits);
    }
    float s[8];
#pragma unroll
    for (int d = 0; d < 8; d++) s[d] = 0.f;
    int stride = gridDim.x * blockDim.x;
    for (int i = blockIdx.x * blockDim.x + threadIdx.x; i < NNODES; i += stride) {
        float4 a = *(const float4*)(L + (size_t)i * 8);
        float4 b = *(const float4*)(L + (size_t)i * 8 + 4);
        float v[8] = {a.x, a.y, a.z, a.w, b.x, b.y, b.z, b.w};
#pragma unroll
        for (int d = 0; d < 8; d++) { v[d] = expf(v[d] - mx[d]); s[d] += v[d]; }
        float4 oa = make_float4(v[0], v[1], v[2], v[3]);
        float4 ob = make_float4(v[4], v[5], v[6], v[7]);
        *(float4*)(L + (size_t)i * 8) = oa;
        *(float4*)(L + (size_t)i * 8 + 4) = ob;
    }
#pragma unroll
    for (int off = 32; off > 0; off >>= 1)
#pragma unroll
        for (int d = 0; d < 8; d++) s[d] += __shfl_down(s[d], off);
    if ((threadIdx.x & 63) == 0) {
#pragma unroll
        for (int d = 0; d < 8; d++) atomicAdd(sums + d, s[d]);
    }
}

// ---------------- pooled reductions: ge[8][64] += attU.T@h2 ; ata[8][8] += attU.T@attU ----
__global__ __launch_bounds__(512) void pooled_kernel(const float* __restrict__ att,
                                                     const float* __restrict__ h2,
                                                     float* __restrict__ ge,
                                                     float* __restrict__ ata) {
    __shared__ float attS[64][8];
    __shared__ float h2S[64][64];
    int t = threadIdx.x;
    int d = t >> 6, j = t & 63;
    int de = t >> 3, ee = t & 7;
    float acc = 0.f, acc2 = 0.f;
    int ntiles = (NNODES + 63) / 64;
    for (int tile = blockIdx.x; tile < ntiles; tile += gridDim.x) {
        int base = tile * 64;
        {
            int i = t >> 3, c = t & 7;
            int row = base + i;
            attS[i][c] = (row < NNODES) ? att[(size_t)row * 8 + c] : 0.f;
        }
#pragma unroll
        for (int q = 0; q < 2; q++) {
            int idx = t + q * 512;
            int i = idx >> 4;
            int c = (idx & 15) * 4;
            int row = base + i;
            float4 v = (row < NNODES) ? *(const float4*)(h2 + (size_t)row * 64 + c)
                                      : make_float4(0.f, 0.f, 0.f, 0.f);
            *(float4*)(&h2S[i][c]) = v;
        }
        __syncthreads();
#pragma unroll 8
        for (int i = 0; i < 64; i++) acc += attS[i][d] * h2S[i][j];
        if (t < 64) {
#pragma unroll 8
            for (int i = 0; i < 64; i++) acc2 += attS[i][de] * attS[i][ee];
        }
        __syncthreads();
    }
    atomicAdd(ge + d * 64 + j, acc);
    if (t < 64) atomicAdd(ata + de * 8 + ee, acc2);
}

// ---------------- tiny epilogue ----------------
__global__ void final_kernel(const float* __restrict__ geacc, const float* __restrict__ ata,
                             const float* __restrict__ colsum, const float* __restrict__ Wl,
                             const float* __restrict__ bl, float* __restrict__ out) {
    __shared__ float geF[512];
    __shared__ float inv[8];
    __shared__ float logits[10];
    int t = threadIdx.x;
    if (t < 8) inv[t] = 1.0f / colsum[t];
    __syncthreads();
    for (int idx = t; idx < 512; idx += 64) {
        int d = idx >> 6;
        float v = geacc[idx] * inv[d];
        geF[idx] = v;
        out[idx] = v;                       // graph_embedding
    }
    __syncthreads();
    if (t == 0) {
        float pen = 0.f;
        for (int d = 0; d < 8; d++) {
            float s = 0.f;
            for (int e = 0; e < 8; e++) {
                float p = ata[d * 8 + e] * inv[d] * inv[e] - (d == e ? 1.0f : 0.0f);
                s += p * p;
            }
            pen += sqrtf(s);
        }
        out[512] = pen;                     // penalty
    }
    if (t < 10) {
        float acc = bl[t];
        for (int k = 0; k < 512; k++) acc += geF[k] * Wl[(size_t)k * 10 + t];
        logits[t] = acc;
    }
    __syncthreads();
    if (t == 0) {
        float m = -INFINITY;
        for (int l = 0; l < 10; l++) m = fmaxf(m, logits[l]);
        float s = 0.f;
        for (int l = 0; l < 10; l++) s += expf(logits[l] - m);
        float ls = logf(s);
        for (int l = 0; l < 10; l++) out[513 + l] = logits[l] - m - ls;  // log_softmax
    }
}

extern "C" void kernel_launch(void* const* d_in, const int* in_sizes, int n_in,
                              void* d_out, int out_size, void* d_ws, size_t ws_size,
                              hipStream_t stream) {
    const int* esrc = (const int*)d_in[0];
    const int* edst = esrc + NEDGES;
    const float* X   = (const float*)d_in[1];
    const float* W1  = (const float*)d_in[2];
    const float* b1  = (const float*)d_in[3];
    const float* W2  = (const float*)d_in[4];
    const float* b2  = (const float*)d_in[5];
    const float* Wf1 = (const float*)d_in[6];
    const float* bf1 = (const float*)d_in[7];
    const float* Wf2 = (const float*)d_in[8];
    const float* bf2 = (const float*)d_in[9];
    const float* Wl  = (const float*)d_in[10];
    const float* bl  = (const float*)d_in[11];
    float* out = (float*)d_out;

    // workspace layout
    float* ws     = (float*)d_ws;
    float* dinv   = ws;                               // N (padded to 100352)
    float* smalls = ws + 100352;                      // 1024
    unsigned* keys = (unsigned*)smalls;               // 8
    float* colsum = smalls + 8;                       // 8
    float* ata    = smalls + 16;                      // 64
    float* geacc  = smalls + 80;                      // 512
    float* A = ws + 101376;                           // N*128
    float* B = A + (size_t)NNODES * 128;              // N*128
    int* row_start = (int*)(B + (size_t)NNODES * 128);// N+1 (padded 100352)
    int* bcnt      = row_start + 100352;              // NBUK (padded 1024)
    int* bstart    = bcnt + 1024;                     // NBUK+1 (padded 1024)
    int* bcur      = bstart + 1024;                   // NBUK (padded 1024)
    int* csr       = bcur + 1024;                     // E
    int* ebuk      = (int*)A;                         // E temp (aliases A; done before gemm1)
    float* L  = A + (size_t)NNODES * 64;              // N*8 (attention logits / attU)
    // aliases: h1 -> B ; hs2 -> A ; h2 -> B ; a1 -> A

    const int nblk_e = (NEDGES + 255) / 256;   // 12500

    // ---- CSR build + dinv (bucketed, dense writes) ----
    init_kernel<<<1, 1024, 0, stream>>>(bcnt, smalls);
    bucket_hist_kernel<<<400, 256, 0, stream>>>(edst, bcnt);
    bucket_scan_kernel<<<1, 1024, 0, stream>>>(bcnt, bstart, bcur, row_start);
    bucket_scatter_kernel<<<nblk_e, 256, 0, stream>>>(esrc, edst, bcur, ebuk);
    build_kernel<<<NBUK, 256, 0, stream>>>(ebuk, bstart, row_start, dinv, csr);

    // ---- GCN layer 1: A = dinv*(X@W1); h1(B) = relu(gather(A)*dinv + b1) ----
    gemm_kernel<128, 128, 0><<<12500, 256, 0, stream>>>(X, W1, nullptr, dinv, A, NNODES);
    gather128_kernel<<<(NNODES + 3) / 4, 256, 0, stream>>>(A, row_start, csr, dinv, b1, B);

    // ---- GCN layer 2: A = dinv*(h1@W2); h2(B) = gather(A)*dinv + b2 ----
    gemm_kernel<128, 64, 0><<<6250, 256, 0, stream>>>(B, W2, nullptr, dinv, A, NNODES);
    gather64_kernel<<<(NNODES + 3) / 4, 256, 0, stream>>>(A, row_start, csr, dinv, b2, B);

    // ---- attention head ----
    gemm_kernel<64, 64, 2><<<6250, 256, 0, stream>>>(B, Wf1, bf1, nullptr, A, NNODES);     // a1=tanh
    gemm_kernel<64, 8, 0><<<(NNODES + 127) / 128, 256, 0, stream>>>(A, Wf2, bf2, nullptr, L, NNODES);
    colmax_kernel<<<256, 256, 0, stream>>>(L, keys);
    colsum_kernel<<<256, 256, 0, stream>>>(L, keys, colsum);
    pooled_kernel<<<256, 512, 0, stream>>>(L, B, geacc, ata);
    final_kernel<<<1, 64, 0, stream>>>(geacc, ata, colsum, Wl, bl, out);
}

// Round 4
// 1113.884 us; speedup vs baseline: 1.6524x; 1.6524x over previous
//
#include <hip/hip_runtime.h>
#include <hip/hip_bf16.h>
#include <math.h>

#define NNODES 100000
#define NEDGES 3200000
#define NBUK ((NNODES + 127) >> 7)   // 782 buckets of 128 nodes
#define NCHUNK 128
#define EPC (NEDGES / NCHUNK)        // 25000 edges per chunk

// ---------------- init: zero small accumulators ----------------
__global__ void init_kernel(float* __restrict__ smalls) {
    int t = threadIdx.x;
    if (t < 592) smalls[t] = 0.0f;   // keys(8) colsum(8) ata(64) ge(512)
}

// ---------------- pass 1: per-chunk bucket histogram (LDS) ----------------
__global__ __launch_bounds__(1024) void chunk_hist_kernel(const int* __restrict__ dst,
                                                          int* __restrict__ hist) {
    __shared__ int h[NBUK];
    int c = blockIdx.x, t = threadIdx.x;
    for (int i = t; i < NBUK; i += 1024) h[i] = 0;
    __syncthreads();
    int e0 = c * EPC, e1 = e0 + EPC;
    for (int e = e0 + t; e < e1; e += 1024)
        atomicAdd(&h[dst[e] >> 7], 1);
    __syncthreads();
    for (int i = t; i < NBUK; i += 1024)
        hist[c * NBUK + i] = h[i];
}

// ---------------- pass 2: per-bucket exclusive prefix over chunks ----------------
__global__ void col_scan_kernel(int* __restrict__ hist, int* __restrict__ btot) {
    int t = blockIdx.x * 256 + threadIdx.x;
    if (t >= NBUK) return;
    int run = 0;
    for (int c = 0; c < NCHUNK; c++) {
        int idx = c * NBUK + t;          // consecutive t -> coalesced
        int v = hist[idx];
        hist[idx] = run;
        run += v;
    }
    btot[t] = run;
}

// ---------------- pass 3: scan bucket totals -> bstart ----------------
__global__ void bucket_scan_kernel(const int* __restrict__ btot, int* __restrict__ bstart,
                                   int* __restrict__ row_start) {
    __shared__ int s[1024];
    int t = threadIdx.x;
    int v = (t < NBUK) ? btot[t] : 0;
    s[t] = v;
    __syncthreads();
    for (int off = 1; off < 1024; off <<= 1) {
        int x = (t >= off) ? s[t - off] : 0;
        __syncthreads();
        s[t] += x;
        __syncthreads();
    }
    if (t < NBUK) bstart[t] = s[t] - v;
    if (t == 0) {
        bstart[NBUK] = NEDGES;
        row_start[NNODES] = NEDGES;
    }
}

// ---------------- pass 4: deterministic scatter into bucket order (LDS cursors) ----------------
__global__ __launch_bounds__(1024) void chunk_scatter_kernel(const int* __restrict__ src,
                                                             const int* __restrict__ dst,
                                                             const int* __restrict__ hist,
                                                             const int* __restrict__ bstart,
                                                             int* __restrict__ ebuk) {
    __shared__ int cur[NBUK];
    int c = blockIdx.x, t = threadIdx.x;
    for (int i = t; i < NBUK; i += 1024)
        cur[i] = bstart[i] + hist[c * NBUK + i];
    __syncthreads();
    int e0 = c * EPC, e1 = e0 + EPC;
    for (int e = e0 + t; e < e1; e += 1024) {
        int d = dst[e];
        int pos = atomicAdd(&cur[d >> 7], 1);
        ebuk[pos] = src[e] | ((d & 127) << 20);   // src < 2^17 fits in 20 bits
    }
}

// ---------------- per-bucket: node counts, row_start, dinv, csr fill ----------------
__global__ __launch_bounds__(256) void build_kernel(const int* __restrict__ ebuk,
                                                    const int* __restrict__ bstart,
                                                    int* __restrict__ row_start,
                                                    float* __restrict__ dinv,
                                                    int* __restrict__ csr) {
    __shared__ int cnt[128];
    __shared__ int cur[128];
    int b = blockIdx.x;
    int t = threadIdx.x;
    int s0 = bstart[b], s1 = bstart[b + 1];
    if (t < 128) cnt[t] = 0;
    __syncthreads();
    for (int i = s0 + t; i < s1; i += 256)
        atomicAdd(&cnt[(ebuk[i] >> 20) & 127], 1);
    __syncthreads();
    if (t == 0) {
        int run = s0;
        for (int i = 0; i < 128; i++) { cur[i] = run; run += cnt[i]; }
    }
    __syncthreads();
    int node = b * 128 + t;
    if (t < 128 && node < NNODES) {
        row_start[node] = cur[t];
        dinv[node] = rsqrtf((float)cnt[t] + 1.0f);
    }
    __syncthreads();
    for (int i = s0 + t; i < s1; i += 256) {
        int v = ebuk[i];
        int pos = atomicAdd(&cur[(v >> 20) & 127], 1);
        csr[pos] = v & 0xFFFFF;
    }
}

// ---------------- generic small-K GEMM: out[N,KOUT] = A[N,KIN] @ W[KIN,KOUT] ----
// optional per-row scale (dinv), bias, activation. ACT: 0 none, 1 relu, 2 tanh
template <int KIN, int KOUT, int ACT>
__global__ __launch_bounds__(256) void gemm_kernel(const float* __restrict__ A,
                                                   const float* __restrict__ W,
                                                   const float* __restrict__ bias,
                                                   const float* __restrict__ rowscale,
                                                   float* __restrict__ out, int nrows) {
    constexpr int ROWS = 1024 / KOUT;      // 256 threads * 4 outputs each
    constexpr int JG   = KOUT / 4;
    __shared__ float As[ROWS][KIN];
    int block_row = blockIdx.x * ROWS;
    int tid = threadIdx.x;

    constexpr int TOT4 = ROWS * KIN / 4;
    const float4* A4 = (const float4*)(A + (size_t)block_row * KIN);
    float4* As4 = (float4*)&As[0][0];
    for (int idx = tid; idx < TOT4; idx += 256) {
        int r = idx / (KIN / 4);
        float4 v = make_float4(0.f, 0.f, 0.f, 0.f);
        if (block_row + r < nrows) v = A4[idx];
        As4[idx] = v;
    }
    __syncthreads();

    int r = tid / JG;
    int j = (tid % JG) * 4;
    float4 acc = make_float4(0.f, 0.f, 0.f, 0.f);
    for (int k = 0; k < KIN; k++) {
        float a = As[r][k];
        float4 w = *(const float4*)(W + (size_t)k * KOUT + j);
        acc.x += a * w.x; acc.y += a * w.y; acc.z += a * w.z; acc.w += a * w.w;
    }
    if (rowscale) {
        float d = rowscale[min(block_row + r, nrows - 1)];
        acc.x *= d; acc.y *= d; acc.z *= d; acc.w *= d;
    }
    if (bias) {
        float4 b4 = *(const float4*)(bias + j);
        acc.x += b4.x; acc.y += b4.y; acc.z += b4.z; acc.w += b4.w;
    }
    if (ACT == 1) {
        acc.x = fmaxf(acc.x, 0.f); acc.y = fmaxf(acc.y, 0.f);
        acc.z = fmaxf(acc.z, 0.f); acc.w = fmaxf(acc.w, 0.f);
    } else if (ACT == 2) {
        acc.x = tanhf(acc.x); acc.y = tanhf(acc.y);
        acc.z = tanhf(acc.z); acc.w = tanhf(acc.w);
    }
    if (block_row + r < nrows)
        *(float4*)(out + (size_t)(block_row + r) * KOUT + j) = acc;
}

// ---------------- gather K=128: one node/wave, 2 lane-halves process 2 edges, float4/lane ----
__global__ __launch_bounds__(256) void gather128_kernel(
    const float* __restrict__ hs, const int* __restrict__ row_start,
    const int* __restrict__ csr, const float* __restrict__ dinv,
    const float* __restrict__ bias, float* __restrict__ out) {
    int wave = threadIdx.x >> 6;
    int lane = threadIdx.x & 63;
    int n = blockIdx.x * 4 + wave;
    if (n >= NNODES) return;
    int half = lane >> 5;      // 0/1: which edge of a pair
    int c4 = lane & 31;        // float4 index within 128-float row
    const float4* rows = (const float4*)hs;   // row stride = 32 float4
    int start = row_start[n], end = row_start[n + 1];
    float4 acc = make_float4(0.f, 0.f, 0.f, 0.f);
    int e = start + half;
    for (; e + 2 < end; e += 4) {             // 2 edges per half in flight
        int s0 = csr[e], s1 = csr[e + 2];
        float4 v0 = rows[(size_t)s0 * 32 + c4];
        float4 v1 = rows[(size_t)s1 * 32 + c4];
        acc.x += v0.x + v1.x; acc.y += v0.y + v1.y;
        acc.z += v0.z + v1.z; acc.w += v0.w + v1.w;
    }
    for (; e < end; e += 2) {
        int s = csr[e];
        float4 v = rows[(size_t)s * 32 + c4];
        acc.x += v.x; acc.y += v.y; acc.z += v.z; acc.w += v.w;
    }
    acc.x += __shfl_xor(acc.x, 32);
    acc.y += __shfl_xor(acc.y, 32);
    acc.z += __shfl_xor(acc.z, 32);
    acc.w += __shfl_xor(acc.w, 32);
    if (half == 0) {
        float4 self = rows[(size_t)n * 32 + c4];
        float d = dinv[n];
        float4 b = ((const float4*)bias)[c4];
        float4 r;
        r.x = fmaxf((acc.x + self.x) * d + b.x, 0.f);
        r.y = fmaxf((acc.y + self.y) * d + b.y, 0.f);
        r.z = fmaxf((acc.z + self.z) * d + b.z, 0.f);
        r.w = fmaxf((acc.w + self.w) * d + b.w, 0.f);
        ((float4*)out)[(size_t)n * 32 + c4] = r;
    }
}

// ---------------- gather K=64: one node/wave, 4 lane-quarters process 4 edges, float4/lane ----
__global__ __launch_bounds__(256) void gather64_kernel(
    const float* __restrict__ hs, const int* __restrict__ row_start,
    const int* __restrict__ csr, const float* __restrict__ dinv,
    const float* __restrict__ bias, float* __restrict__ out) {
    int wave = threadIdx.x >> 6;
    int lane = threadIdx.x & 63;
    int n = blockIdx.x * 4 + wave;
    if (n >= NNODES) return;
    int q = lane >> 4;         // 0..3: which edge of a quad
    int c4 = lane & 15;        // float4 index within 64-float row
    const float4* rows = (const float4*)hs;   // row stride = 16 float4
    int start = row_start[n], end = row_start[n + 1];
    float4 acc = make_float4(0.f, 0.f, 0.f, 0.f);
    int e = start + q;
    for (; e + 4 < end; e += 8) {             // 2 edges per quarter in flight
        int s0 = csr[e], s1 = csr[e + 4];
        float4 v0 = rows[(size_t)s0 * 16 + c4];
        float4 v1 = rows[(size_t)s1 * 16 + c4];
        acc.x += v0.x + v1.x; acc.y += v0.y + v1.y;
        acc.z += v0.z + v1.z; acc.w += v0.w + v1.w;
    }
    for (; e < end; e += 4) {
        int s = csr[e];
        float4 v = rows[(size_t)s * 16 + c4];
        acc.x += v.x; acc.y += v.y; acc.z += v.z; acc.w += v.w;
    }
#pragma unroll
    for (int off = 16; off <= 32; off <<= 1) {
        acc.x += __shfl_xor(acc.x, off);
        acc.y += __shfl_xor(acc.y, off);
        acc.z += __shfl_xor(acc.z, off);
        acc.w += __shfl_xor(acc.w, off);
    }
    if (lane < 16) {
        float4 self = rows[(size_t)n * 16 + c4];
        float d = dinv[n];
        float4 b = ((const float4*)bias)[c4];
        float4 r;
        r.x = (acc.x + self.x) * d + b.x;
        r.y = (acc.y + self.y) * d + b.y;
        r.z = (acc.z + self.z) * d + b.z;
        r.w = (acc.w + self.w) * d + b.w;
        ((float4*)out)[(size_t)n * 16 + c4] = r;
    }
}

// ---------------- column max over N for 8 columns (ordered-uint atomicMax) ----------------
__global__ void colmax_kernel(const float* __restrict__ L, unsigned* __restrict__ keys) {
    float m[8];
#pragma unroll
    for (int d = 0; d < 8; d++) m[d] = -INFINITY;
    int stride = gridDim.x * blockDim.x;
    for (int i = blockIdx.x * blockDim.x + threadIdx.x; i < NNODES; i += stride) {
        float4 a = *(const float4*)(L + (size_t)i * 8);
        float4 b = *(const float4*)(L + (size_t)i * 8 + 4);
        m[0] = fmaxf(m[0], a.x); m[1] = fmaxf(m[1], a.y);
        m[2] = fmaxf(m[2], a.z); m[3] = fmaxf(m[3], a.w);
        m[4] = fmaxf(m[4], b.x); m[5] = fmaxf(m[5], b.y);
        m[6] = fmaxf(m[6], b.z); m[7] = fmaxf(m[7], b.w);
    }
#pragma unroll
    for (int off = 32; off > 0; off >>= 1)
#pragma unroll
        for (int d = 0; d < 8; d++) m[d] = fmaxf(m[d], __shfl_down(m[d], off));
    if ((threadIdx.x & 63) == 0) {
#pragma unroll
        for (int d = 0; d < 8; d++) {
            unsigned bits = __float_as_uint(m[d]);
            unsigned key = (bits & 0x80000000u) ? ~bits : (bits | 0x80000000u);
            atomicMax(keys + d, key);
        }
    }
}

// ---------------- exp(L - max) in place, column sums ----------------
__global__ void colsum_kernel(float* __restrict__ L, const unsigned* __restrict__ keys,
                              float* __restrict__ sums) {
    float mx[8];
#pragma unroll
    for (int d = 0; d < 8; d++) {
        unsigned key = keys[d];
        unsigned bits = (key & 0x80000000u) ? (key ^ 0x80000000u) : ~key;
        mx[d] = __uint_as_float(bits);
    }
    float s[8];
#pragma unroll
    for (int d = 0; d < 8; d++) s[d] = 0.f;
    int stride = gridDim.x * blockDim.x;
    for (int i = blockIdx.x * blockDim.x + threadIdx.x; i < NNODES; i += stride) {
        float4 a = *(const float4*)(L + (size_t)i * 8);
        float4 b = *(const float4*)(L + (size_t)i * 8 + 4);
        float v[8] = {a.x, a.y, a.z, a.w, b.x, b.y, b.z, b.w};
#pragma unroll
        for (int d = 0; d < 8; d++) { v[d] = expf(v[d] - mx[d]); s[d] += v[d]; }
        float4 oa = make_float4(v[0], v[1], v[2], v[3]);
        float4 ob = make_float4(v[4], v[5], v[6], v[7]);
        *(float4*)(L + (size_t)i * 8) = oa;
        *(float4*)(L + (size_t)i * 8 + 4) = ob;
    }
#pragma unroll
    for (int off = 32; off > 0; off >>= 1)
#pragma unroll
        for (int d = 0; d < 8; d++) s[d] += __shfl_down(s[d], off);
    if ((threadIdx.x & 63) == 0) {
#pragma unroll
        for (int d = 0; d < 8; d++) atomicAdd(sums + d, s[d]);
    }
}

// ---------------- pooled reductions: ge[8][64] += attU.T@h2 ; ata[8][8] += attU.T@attU ----
__global__ __launch_bounds__(512) void pooled_kernel(const float* __restrict__ att,
                                                     const float* __restrict__ h2,
                                                     float* __restrict__ ge,
                                                     float* __restrict__ ata) {
    __shared__ float attS[64][8];
    __shared__ float h2S[64][64];
    int t = threadIdx.x;
    int d = t >> 6, j = t & 63;
    int de = t >> 3, ee = t & 7;
    float acc = 0.f, acc2 = 0.f;
    int ntiles = (NNODES + 63) / 64;
    for (int tile = blockIdx.x; tile < ntiles; tile += gridDim.x) {
        int base = tile * 64;
        {
            int i = t >> 3, c = t & 7;
            int row = base + i;
            attS[i][c] = (row < NNODES) ? att[(size_t)row * 8 + c] : 0.f;
        }
#pragma unroll
        for (int q = 0; q < 2; q++) {
            int idx = t + q * 512;
            int i = idx >> 4;
            int c = (idx & 15) * 4;
            int row = base + i;
            float4 v = (row < NNODES) ? *(const float4*)(h2 + (size_t)row * 64 + c)
                                      : make_float4(0.f, 0.f, 0.f, 0.f);
            *(float4*)(&h2S[i][c]) = v;
        }
        __syncthreads();
#pragma unroll 8
        for (int i = 0; i < 64; i++) acc += attS[i][d] * h2S[i][j];
        if (t < 64) {
#pragma unroll 8
            for (int i = 0; i < 64; i++) acc2 += attS[i][de] * attS[i][ee];
        }
        __syncthreads();
    }
    atomicAdd(ge + d * 64 + j, acc);
    if (t < 64) atomicAdd(ata + de * 8 + ee, acc2);
}

// ---------------- tiny epilogue ----------------
__global__ void final_kernel(const float* __restrict__ geacc, const float* __restrict__ ata,
                             const float* __restrict__ colsum, const float* __restrict__ Wl,
                             const float* __restrict__ bl, float* __restrict__ out) {
    __shared__ float geF[512];
    __shared__ float inv[8];
    __shared__ float logits[10];
    int t = threadIdx.x;
    if (t < 8) inv[t] = 1.0f / colsum[t];
    __syncthreads();
    for (int idx = t; idx < 512; idx += 64) {
        int d = idx >> 6;
        float v = geacc[idx] * inv[d];
        geF[idx] = v;
        out[idx] = v;                       // graph_embedding
    }
    __syncthreads();
    if (t == 0) {
        float pen = 0.f;
        for (int d = 0; d < 8; d++) {
            float s = 0.f;
            for (int e = 0; e < 8; e++) {
                float p = ata[d * 8 + e] * inv[d] * inv[e] - (d == e ? 1.0f : 0.0f);
                s += p * p;
            }
            pen += sqrtf(s);
        }
        out[512] = pen;                     // penalty
    }
    if (t < 10) {
        float acc = bl[t];
        for (int k = 0; k < 512; k++) acc += geF[k] * Wl[(size_t)k * 10 + t];
        logits[t] = acc;
    }
    __syncthreads();
    if (t == 0) {
        float m = -INFINITY;
        for (int l = 0; l < 10; l++) m = fmaxf(m, logits[l]);
        float s = 0.f;
        for (int l = 0; l < 10; l++) s += expf(logits[l] - m);
        float ls = logf(s);
        for (int l = 0; l < 10; l++) out[513 + l] = logits[l] - m - ls;  // log_softmax
    }
}

extern "C" void kernel_launch(void* const* d_in, const int* in_sizes, int n_in,
                              void* d_out, int out_size, void* d_ws, size_t ws_size,
                              hipStream_t stream) {
    const int* esrc = (const int*)d_in[0];
    const int* edst = esrc + NEDGES;
    const float* X   = (const float*)d_in[1];
    const float* W1  = (const float*)d_in[2];
    const float* b1  = (const float*)d_in[3];
    const float* W2  = (const float*)d_in[4];
    const float* b2  = (const float*)d_in[5];
    const float* Wf1 = (const float*)d_in[6];
    const float* bf1 = (const float*)d_in[7];
    const float* Wf2 = (const float*)d_in[8];
    const float* bf2 = (const float*)d_in[9];
    const float* Wl  = (const float*)d_in[10];
    const float* bl  = (const float*)d_in[11];
    float* out = (float*)d_out;

    // workspace layout
    float* ws     = (float*)d_ws;
    float* dinv   = ws;                               // N (padded to 100352)
    float* smalls = ws + 100352;                      // 1024
    unsigned* keys = (unsigned*)smalls;               // 8
    float* colsum = smalls + 8;                       // 8
    float* ata    = smalls + 16;                      // 64
    float* geacc  = smalls + 80;                      // 512
    float* A = ws + 101376;                           // N*128
    float* B = A + (size_t)NNODES * 128;              // N*128
    int* row_start = (int*)(B + (size_t)NNODES * 128);// N+1 (padded 100352)
    int* btot      = row_start + 100352;              // NBUK (padded 1024)
    int* bstart    = btot + 1024;                     // NBUK+1 (padded 1024)
    int* csr       = bstart + 1024;                   // E
    int* ebuk      = (int*)A;                         // E temp (aliases A; consumed before gemm1)
    int* hist      = (int*)B;                         // NCHUNK*NBUK temp (aliases B; consumed before gather128)
    float* L  = A + (size_t)NNODES * 64;              // N*8 (attention logits / attU)
    // aliases: h1 -> B ; hs2 -> A ; h2 -> B ; a1 -> A

    // ---- CSR build + dinv (deterministic two-pass counting sort) ----
    init_kernel<<<1, 1024, 0, stream>>>(smalls);
    chunk_hist_kernel<<<NCHUNK, 1024, 0, stream>>>(edst, hist);
    col_scan_kernel<<<4, 256, 0, stream>>>(hist, btot);
    bucket_scan_kernel<<<1, 1024, 0, stream>>>(btot, bstart, row_start);
    chunk_scatter_kernel<<<NCHUNK, 1024, 0, stream>>>(esrc, edst, hist, bstart, ebuk);
    build_kernel<<<NBUK, 256, 0, stream>>>(ebuk, bstart, row_start, dinv, csr);

    // ---- GCN layer 1: A = dinv*(X@W1); h1(B) = relu(gather(A)*dinv + b1) ----
    gemm_kernel<128, 128, 0><<<12500, 256, 0, stream>>>(X, W1, nullptr, dinv, A, NNODES);
    gather128_kernel<<<(NNODES + 3) / 4, 256, 0, stream>>>(A, row_start, csr, dinv, b1, B);

    // ---- GCN layer 2: A = dinv*(h1@W2); h2(B) = gather(A)*dinv + b2 ----
    gemm_kernel<128, 64, 0><<<6250, 256, 0, stream>>>(B, W2, nullptr, dinv, A, NNODES);
    gather64_kernel<<<(NNODES + 3) / 4, 256, 0, stream>>>(A, row_start, csr, dinv, b2, B);

    // ---- attention head ----
    gemm_kernel<64, 64, 2><<<6250, 256, 0, stream>>>(B, Wf1, bf1, nullptr, A, NNODES);     // a1=tanh
    gemm_kernel<64, 8, 0><<<(NNODES + 127) / 128, 256, 0, stream>>>(A, Wf2, bf2, nullptr, L, NNODES);
    colmax_kernel<<<256, 256, 0, stream>>>(L, keys);
    colsum_kernel<<<256, 256, 0, stream>>>(L, keys, colsum);
    pooled_kernel<<<256, 512, 0, stream>>>(L, B, geacc, ata);
    final_kernel<<<1, 64, 0, stream>>>(geacc, ata, colsum, Wl, bl, out);
}

// Round 5
// 826.076 us; speedup vs baseline: 2.2281x; 1.3484x over previous
//
#include <hip/hip_runtime.h>
#include <hip/hip_bf16.h>
#include <math.h>

#define NNODES 100000
#define NEDGES 3200000
#define NBUK ((NNODES + 127) >> 7)   // 782 buckets of 128 nodes
#define NCHUNK 128
#define EPC (NEDGES / NCHUNK)        // 25000 edges per chunk

// ---- bf16 helpers (RNE pack; unpack via shift) ----
__device__ __forceinline__ unsigned short f2bf(float x) {
    unsigned u = __float_as_uint(x);
    unsigned r = u + 0x7FFFu + ((u >> 16) & 1u);
    return (unsigned short)(r >> 16);
}
__device__ __forceinline__ void unpack8(uint4 v, float* f) {
    f[0] = __uint_as_float(v.x << 16); f[1] = __uint_as_float(v.x & 0xFFFF0000u);
    f[2] = __uint_as_float(v.y << 16); f[3] = __uint_as_float(v.y & 0xFFFF0000u);
    f[4] = __uint_as_float(v.z << 16); f[5] = __uint_as_float(v.z & 0xFFFF0000u);
    f[6] = __uint_as_float(v.w << 16); f[7] = __uint_as_float(v.w & 0xFFFF0000u);
}

// ---------------- init: zero small accumulators ----------------
__global__ void init_kernel(float* __restrict__ smalls) {
    int t = threadIdx.x;
    if (t < 592) smalls[t] = 0.0f;   // colsum(8) ata(64) ge(512) (+spare)
}

// ---------------- pass 1: per-chunk bucket histogram (LDS) ----------------
__global__ __launch_bounds__(1024) void chunk_hist_kernel(const int* __restrict__ dst,
                                                          int* __restrict__ hist) {
    __shared__ int h[NBUK];
    int c = blockIdx.x, t = threadIdx.x;
    for (int i = t; i < NBUK; i += 1024) h[i] = 0;
    __syncthreads();
    int e0 = c * EPC, e1 = e0 + EPC;
    for (int e = e0 + t; e < e1; e += 1024)
        atomicAdd(&h[dst[e] >> 7], 1);
    __syncthreads();
    for (int i = t; i < NBUK; i += 1024)
        hist[c * NBUK + i] = h[i];
}

// ---------------- pass 2: per-bucket exclusive prefix over chunks ----------------
__global__ void col_scan_kernel(int* __restrict__ hist, int* __restrict__ btot) {
    int t = blockIdx.x * 256 + threadIdx.x;
    if (t >= NBUK) return;
    int run = 0;
    for (int c = 0; c < NCHUNK; c++) {
        int idx = c * NBUK + t;
        int v = hist[idx];
        hist[idx] = run;
        run += v;
    }
    btot[t] = run;
}

// ---------------- pass 3: scan bucket totals -> bstart ----------------
__global__ void bucket_scan_kernel(const int* __restrict__ btot, int* __restrict__ bstart,
                                   int* __restrict__ row_start) {
    __shared__ int s[1024];
    int t = threadIdx.x;
    int v = (t < NBUK) ? btot[t] : 0;
    s[t] = v;
    __syncthreads();
    for (int off = 1; off < 1024; off <<= 1) {
        int x = (t >= off) ? s[t - off] : 0;
        __syncthreads();
        s[t] += x;
        __syncthreads();
    }
    if (t < NBUK) bstart[t] = s[t] - v;
    if (t == 0) {
        bstart[NBUK] = NEDGES;
        row_start[NNODES] = NEDGES;
    }
}

// ---------------- pass 4: deterministic scatter into bucket order (LDS cursors) ----------------
__global__ __launch_bounds__(1024) void chunk_scatter_kernel(const int* __restrict__ src,
                                                             const int* __restrict__ dst,
                                                             const int* __restrict__ hist,
                                                             const int* __restrict__ bstart,
                                                             int* __restrict__ ebuk) {
    __shared__ int cur[NBUK];
    int c = blockIdx.x, t = threadIdx.x;
    for (int i = t; i < NBUK; i += 1024)
        cur[i] = bstart[i] + hist[c * NBUK + i];
    __syncthreads();
    int e0 = c * EPC, e1 = e0 + EPC;
    for (int e = e0 + t; e < e1; e += 1024) {
        int d = dst[e];
        int pos = atomicAdd(&cur[d >> 7], 1);
        ebuk[pos] = src[e] | ((d & 127) << 20);   // src < 2^17 fits in 20 bits
    }
}

// ---------------- per-bucket: node counts, row_start, dinv, csr fill ----------------
__global__ __launch_bounds__(256) void build_kernel(const int* __restrict__ ebuk,
                                                    const int* __restrict__ bstart,
                                                    int* __restrict__ row_start,
                                                    float* __restrict__ dinv,
                                                    int* __restrict__ csr) {
    __shared__ int cnt[128];
    __shared__ int cur[128];
    int b = blockIdx.x;
    int t = threadIdx.x;
    int s0 = bstart[b], s1 = bstart[b + 1];
    if (t < 128) cnt[t] = 0;
    __syncthreads();
    for (int i = s0 + t; i < s1; i += 256)
        atomicAdd(&cnt[(ebuk[i] >> 20) & 127], 1);
    __syncthreads();
    if (t == 0) {
        int run = s0;
        for (int i = 0; i < 128; i++) { cur[i] = run; run += cnt[i]; }
    }
    __syncthreads();
    int node = b * 128 + t;
    if (t < 128 && node < NNODES) {
        row_start[node] = cur[t];
        dinv[node] = rsqrtf((float)cnt[t] + 1.0f);
    }
    __syncthreads();
    for (int i = s0 + t; i < s1; i += 256) {
        int v = ebuk[i];
        int pos = atomicAdd(&cur[(v >> 20) & 127], 1);
        csr[pos] = v & 0xFFFFF;
    }
}

// ---------------- GEMM: stage[N,KOUT](bf16) = rowscale * (A[N,KIN] @ W[KIN,KOUT]) ----------------
template <int KIN, int KOUT>
__global__ __launch_bounds__(256) void gemm_stage_kernel(const float* __restrict__ A,
                                                         const float* __restrict__ W,
                                                         const float* __restrict__ rowscale,
                                                         unsigned short* __restrict__ stage,
                                                         int nrows) {
    constexpr int ROWS = 1024 / KOUT;
    constexpr int JG   = KOUT / 4;
    __shared__ float As[ROWS][KIN];
    int block_row = blockIdx.x * ROWS;
    int tid = threadIdx.x;

    constexpr int TOT4 = ROWS * KIN / 4;
    const float4* A4 = (const float4*)(A + (size_t)block_row * KIN);
    float4* As4 = (float4*)&As[0][0];
    for (int idx = tid; idx < TOT4; idx += 256) {
        int r = idx / (KIN / 4);
        float4 v = make_float4(0.f, 0.f, 0.f, 0.f);
        if (block_row + r < nrows) v = A4[idx];
        As4[idx] = v;
    }
    __syncthreads();

    int r = tid / JG;
    int j = (tid % JG) * 4;
    float4 acc = make_float4(0.f, 0.f, 0.f, 0.f);
    for (int k = 0; k < KIN; k++) {
        float a = As[r][k];
        float4 w = *(const float4*)(W + (size_t)k * KOUT + j);
        acc.x += a * w.x; acc.y += a * w.y; acc.z += a * w.z; acc.w += a * w.w;
    }
    float d = rowscale[min(block_row + r, nrows - 1)];
    acc.x *= d; acc.y *= d; acc.z *= d; acc.w *= d;
    if (block_row + r < nrows) {
        ushort4 p;
        p.x = f2bf(acc.x); p.y = f2bf(acc.y); p.z = f2bf(acc.z); p.w = f2bf(acc.w);
        *(ushort4*)(stage + (size_t)(block_row + r) * KOUT + j) = p;
    }
}

// ---------------- gather K=128 bf16: one node/wave, 4 lane-quads, uint4(8 bf16)/lane ----------------
__global__ __launch_bounds__(256) void gather128_kernel(
    const unsigned short* __restrict__ hs, const int* __restrict__ row_start,
    const int* __restrict__ csr, const float* __restrict__ dinv,
    const float* __restrict__ bias, float* __restrict__ out) {
    int wave = threadIdx.x >> 6;
    int lane = threadIdx.x & 63;
    int n = blockIdx.x * 4 + wave;
    if (n >= NNODES) return;
    int q = lane >> 4;       // 0..3: edge sub-group
    int c = lane & 15;       // uint4 index within 256 B row
    const uint4* rows = (const uint4*)hs;    // row stride = 16 uint4
    int start = row_start[n], end = row_start[n + 1];
    float acc[8];
#pragma unroll
    for (int i = 0; i < 8; i++) acc[i] = 0.f;
    float f[8];
    int e = start + q;
    for (; e + 4 < end; e += 8) {
        uint4 v0 = rows[(size_t)csr[e] * 16 + c];
        uint4 v1 = rows[(size_t)csr[e + 4] * 16 + c];
        unpack8(v0, f);
#pragma unroll
        for (int i = 0; i < 8; i++) acc[i] += f[i];
        unpack8(v1, f);
#pragma unroll
        for (int i = 0; i < 8; i++) acc[i] += f[i];
    }
    for (; e < end; e += 4) {
        uint4 v = rows[(size_t)csr[e] * 16 + c];
        unpack8(v, f);
#pragma unroll
        for (int i = 0; i < 8; i++) acc[i] += f[i];
    }
#pragma unroll
    for (int off = 16; off <= 32; off <<= 1)
#pragma unroll
        for (int i = 0; i < 8; i++) acc[i] += __shfl_xor(acc[i], off);
    if (q == 0) {
        uint4 sv = rows[(size_t)n * 16 + c];
        unpack8(sv, f);
        float d = dinv[n];
        float4 b0 = ((const float4*)bias)[c * 2];
        float4 b1 = ((const float4*)bias)[c * 2 + 1];
        float4 r0, r1;
        r0.x = fmaxf((acc[0] + f[0]) * d + b0.x, 0.f);
        r0.y = fmaxf((acc[1] + f[1]) * d + b0.y, 0.f);
        r0.z = fmaxf((acc[2] + f[2]) * d + b0.z, 0.f);
        r0.w = fmaxf((acc[3] + f[3]) * d + b0.w, 0.f);
        r1.x = fmaxf((acc[4] + f[4]) * d + b1.x, 0.f);
        r1.y = fmaxf((acc[5] + f[5]) * d + b1.y, 0.f);
        r1.z = fmaxf((acc[6] + f[6]) * d + b1.z, 0.f);
        r1.w = fmaxf((acc[7] + f[7]) * d + b1.w, 0.f);
        float4* o = (float4*)(out + (size_t)n * 128 + c * 8);
        o[0] = r0; o[1] = r1;
    }
}

// ---------------- gather K=64 bf16: one node/wave, 8 lane-octets, uint4/lane ----------------
__global__ __launch_bounds__(256) void gather64_kernel(
    const unsigned short* __restrict__ hs, const int* __restrict__ row_start,
    const int* __restrict__ csr, const float* __restrict__ dinv,
    const float* __restrict__ bias, float* __restrict__ out) {
    int wave = threadIdx.x >> 6;
    int lane = threadIdx.x & 63;
    int n = blockIdx.x * 4 + wave;
    if (n >= NNODES) return;
    int g = lane >> 3;       // 0..7: edge sub-group
    int c = lane & 7;        // uint4 index within 128 B row
    const uint4* rows = (const uint4*)hs;    // row stride = 8 uint4
    int start = row_start[n], end = row_start[n + 1];
    float acc[8];
#pragma unroll
    for (int i = 0; i < 8; i++) acc[i] = 0.f;
    float f[8];
    int e = start + g;
    for (; e + 8 < end; e += 16) {
        uint4 v0 = rows[(size_t)csr[e] * 8 + c];
        uint4 v1 = rows[(size_t)csr[e + 8] * 8 + c];
        unpack8(v0, f);
#pragma unroll
        for (int i = 0; i < 8; i++) acc[i] += f[i];
        unpack8(v1, f);
#pragma unroll
        for (int i = 0; i < 8; i++) acc[i] += f[i];
    }
    for (; e < end; e += 8) {
        uint4 v = rows[(size_t)csr[e] * 8 + c];
        unpack8(v, f);
#pragma unroll
        for (int i = 0; i < 8; i++) acc[i] += f[i];
    }
#pragma unroll
    for (int off = 8; off <= 32; off <<= 1)
#pragma unroll
        for (int i = 0; i < 8; i++) acc[i] += __shfl_xor(acc[i], off);
    if (lane < 8) {
        uint4 sv = rows[(size_t)n * 8 + c];
        unpack8(sv, f);
        float d = dinv[n];
        float4 b0 = ((const float4*)bias)[c * 2];
        float4 b1 = ((const float4*)bias)[c * 2 + 1];
        float4 r0, r1;
        r0.x = (acc[0] + f[0]) * d + b0.x;
        r0.y = (acc[1] + f[1]) * d + b0.y;
        r0.z = (acc[2] + f[2]) * d + b0.z;
        r0.w = (acc[3] + f[3]) * d + b0.w;
        r1.x = (acc[4] + f[4]) * d + b1.x;
        r1.y = (acc[5] + f[5]) * d + b1.y;
        r1.z = (acc[6] + f[6]) * d + b1.z;
        r1.w = (acc[7] + f[7]) * d + b1.w;
        float4* o = (float4*)(out + (size_t)n * 64 + c * 8);
        o[0] = r0; o[1] = r1;
    }
}

// ---------------- fused attention head: att = exp(tanh(h2@Wf1+bf1)@Wf2+bf2), colsum ----------------
// 16 rows per block, N = 6250 * 16 exactly.
__global__ __launch_bounds__(256) void attn_kernel(const float* __restrict__ h2,
                                                   const float* __restrict__ Wf1,
                                                   const float* __restrict__ bf1,
                                                   const float* __restrict__ Wf2,
                                                   const float* __restrict__ bf2,
                                                   float* __restrict__ att,
                                                   float* __restrict__ colsum) {
    __shared__ float h2S[16][64];
    __shared__ float a1S[16][65];
    __shared__ float colS[8][16];
    int t = threadIdx.x;
    int base = blockIdx.x * 16;
    // load h2 tile: 256 float4
    {
        int i = t >> 4, c = (t & 15) * 4;
        *(float4*)(&h2S[i][c]) = *(const float4*)(h2 + (size_t)(base + i) * 64 + c);
    }
    __syncthreads();
    // phase 1: a1 = tanh(h2 @ Wf1 + bf1)
    {
        int r = t >> 4, j = (t & 15) * 4;
        float4 acc = *(const float4*)(bf1 + j);
        for (int k = 0; k < 64; k++) {
            float a = h2S[r][k];
            float4 w = *(const float4*)(Wf1 + (size_t)k * 64 + j);
            acc.x += a * w.x; acc.y += a * w.y; acc.z += a * w.z; acc.w += a * w.w;
        }
        a1S[r][j]     = tanhf(acc.x);
        a1S[r][j + 1] = tanhf(acc.y);
        a1S[r][j + 2] = tanhf(acc.z);
        a1S[r][j + 3] = tanhf(acc.w);
    }
    __syncthreads();
    // phase 2: att = exp(a1 @ Wf2 + bf2); per-block column partial sums
    if (t < 128) {
        int r = t >> 3, c = t & 7;
        float acc = bf2[c];
        for (int k = 0; k < 64; k++)
            acc += a1S[r][k] * Wf2[(size_t)k * 8 + c];
        float ev = __expf(acc);
        att[(size_t)(base + r) * 8 + c] = ev;
        colS[c][r] = ev;
    }
    __syncthreads();
    if (t < 8) {
        float s = 0.f;
#pragma unroll
        for (int r = 0; r < 16; r++) s += colS[t][r];
        atomicAdd(colsum + t, s);
    }
}

// ---------------- pooled reductions: ge[8][64] += attU.T@h2 ; ata[8][8] += attU.T@attU ----
__global__ __launch_bounds__(512) void pooled_kernel(const float* __restrict__ att,
                                                     const float* __restrict__ h2,
                                                     float* __restrict__ ge,
                                                     float* __restrict__ ata) {
    __shared__ float attS[64][8];
    __shared__ float h2S[64][64];
    int t = threadIdx.x;
    int d = t >> 6, j = t & 63;
    int de = t >> 3, ee = t & 7;
    float acc = 0.f, acc2 = 0.f;
    int ntiles = (NNODES + 63) / 64;
    for (int tile = blockIdx.x; tile < ntiles; tile += gridDim.x) {
        int base = tile * 64;
        {
            int i = t >> 3, c = t & 7;
            int row = base + i;
            attS[i][c] = (row < NNODES) ? att[(size_t)row * 8 + c] : 0.f;
        }
#pragma unroll
        for (int q = 0; q < 2; q++) {
            int idx = t + q * 512;
            int i = idx >> 4;
            int c = (idx & 15) * 4;
            int row = base + i;
            float4 v = (row < NNODES) ? *(const float4*)(h2 + (size_t)row * 64 + c)
                                      : make_float4(0.f, 0.f, 0.f, 0.f);
            *(float4*)(&h2S[i][c]) = v;
        }
        __syncthreads();
#pragma unroll 8
        for (int i = 0; i < 64; i++) acc += attS[i][d] * h2S[i][j];
        if (t < 64) {
#pragma unroll 8
            for (int i = 0; i < 64; i++) acc2 += attS[i][de] * attS[i][ee];
        }
        __syncthreads();
    }
    atomicAdd(ge + d * 64 + j, acc);
    if (t < 64) atomicAdd(ata + de * 8 + ee, acc2);
}

// ---------------- tiny epilogue ----------------
__global__ void final_kernel(const float* __restrict__ geacc, const float* __restrict__ ata,
                             const float* __restrict__ colsum, const float* __restrict__ Wl,
                             const float* __restrict__ bl, float* __restrict__ out) {
    __shared__ float geF[512];
    __shared__ float inv[8];
    __shared__ float logits[10];
    int t = threadIdx.x;
    if (t < 8) inv[t] = 1.0f / colsum[t];
    __syncthreads();
    for (int idx = t; idx < 512; idx += 64) {
        int d = idx >> 6;
        float v = geacc[idx] * inv[d];
        geF[idx] = v;
        out[idx] = v;                       // graph_embedding
    }
    __syncthreads();
    if (t == 0) {
        float pen = 0.f;
        for (int d = 0; d < 8; d++) {
            float s = 0.f;
            for (int e = 0; e < 8; e++) {
                float p = ata[d * 8 + e] * inv[d] * inv[e] - (d == e ? 1.0f : 0.0f);
                s += p * p;
            }
            pen += sqrtf(s);
        }
        out[512] = pen;                     // penalty
    }
    if (t < 10) {
        float acc = bl[t];
        for (int k = 0; k < 512; k++) acc += geF[k] * Wl[(size_t)k * 10 + t];
        logits[t] = acc;
    }
    __syncthreads();
    if (t == 0) {
        float m = -INFINITY;
        for (int l = 0; l < 10; l++) m = fmaxf(m, logits[l]);
        float s = 0.f;
        for (int l = 0; l < 10; l++) s += expf(logits[l] - m);
        float ls = logf(s);
        for (int l = 0; l < 10; l++) out[513 + l] = logits[l] - m - ls;  // log_softmax
    }
}

extern "C" void kernel_launch(void* const* d_in, const int* in_sizes, int n_in,
                              void* d_out, int out_size, void* d_ws, size_t ws_size,
                              hipStream_t stream) {
    const int* esrc = (const int*)d_in[0];
    const int* edst = esrc + NEDGES;
    const float* X   = (const float*)d_in[1];
    const float* W1  = (const float*)d_in[2];
    const float* b1  = (const float*)d_in[3];
    const float* W2  = (const float*)d_in[4];
    const float* b2  = (const float*)d_in[5];
    const float* Wf1 = (const float*)d_in[6];
    const float* bf1 = (const float*)d_in[7];
    const float* Wf2 = (const float*)d_in[8];
    const float* bf2 = (const float*)d_in[9];
    const float* Wl  = (const float*)d_in[10];
    const float* bl  = (const float*)d_in[11];
    float* out = (float*)d_out;

    // workspace layout
    float* ws     = (float*)d_ws;
    float* dinv   = ws;                               // N (padded to 100352)
    float* smalls = ws + 100352;                      // 1024
    float* colsum = smalls + 8;                       // 8
    float* ata    = smalls + 16;                      // 64
    float* geacc  = smalls + 80;                      // 512
    float* A = ws + 101376;                           // N*128 fp32 region
    float* B = A + (size_t)NNODES * 128;              // N*128 fp32 region
    int* row_start = (int*)(B + (size_t)NNODES * 128);// N+1 (padded 100352)
    int* btot      = row_start + 100352;              // NBUK (padded 1024)
    int* bstart    = btot + 1024;                     // NBUK+1 (padded 1024)
    int* csr       = bstart + 1024;                   // E
    int* ebuk      = (int*)A;                         // E temp (consumed before gemm1 writes A)
    int* hist      = (int*)B;                         // NCHUNK*NBUK temp (consumed before gather128 writes B)
    unsigned short* stage = (unsigned short*)A;       // bf16 staging (N*128 or N*64)
    float* h1  = B;                                   // N*128 fp32
    float* h2  = B;                                   // N*64 fp32 (overwrites h1)
    float* L   = A;                                   // N*8 fp32 (att, after staging consumed)

    // ---- CSR build + dinv (deterministic two-pass counting sort) ----
    init_kernel<<<1, 1024, 0, stream>>>(smalls);
    chunk_hist_kernel<<<NCHUNK, 1024, 0, stream>>>(edst, hist);
    col_scan_kernel<<<4, 256, 0, stream>>>(hist, btot);
    bucket_scan_kernel<<<1, 1024, 0, stream>>>(btot, bstart, row_start);
    chunk_scatter_kernel<<<NCHUNK, 1024, 0, stream>>>(esrc, edst, hist, bstart, ebuk);
    build_kernel<<<NBUK, 256, 0, stream>>>(ebuk, bstart, row_start, dinv, csr);

    // ---- GCN layer 1: stage = bf16(dinv*(X@W1)); h1 = relu(gather(stage)*dinv + b1) ----
    gemm_stage_kernel<128, 128><<<12500, 256, 0, stream>>>(X, W1, dinv, stage, NNODES);
    gather128_kernel<<<(NNODES + 3) / 4, 256, 0, stream>>>(stage, row_start, csr, dinv, b1, h1);

    // ---- GCN layer 2: stage = bf16(dinv*(h1@W2)); h2 = gather(stage)*dinv + b2 ----
    gemm_stage_kernel<128, 64><<<6250, 256, 0, stream>>>(h1, W2, dinv, stage, NNODES);
    gather64_kernel<<<(NNODES + 3) / 4, 256, 0, stream>>>(stage, row_start, csr, dinv, b2, h2);

    // ---- fused attention head: att(L) = exp(tanh(h2@Wf1+bf1)@Wf2+bf2), colsum ----
    attn_kernel<<<6250, 256, 0, stream>>>(h2, Wf1, bf1, Wf2, bf2, L, colsum);

    // ---- pooling + epilogue ----
    pooled_kernel<<<512, 512, 0, stream>>>(L, h2, geacc, ata);
    final_kernel<<<1, 64, 0, stream>>>(geacc, ata, colsum, Wl, bl, out);
}

// Round 6
// 554.470 us; speedup vs baseline: 3.3196x; 1.4898x over previous
//
#include <hip/hip_runtime.h>
#include <hip/hip_bf16.h>
#include <math.h>

#define NNODES 100000
#define NEDGES 3200000
#define NBUK ((NNODES + 127) >> 7)   // 782 buckets of 128 nodes
#define NCHUNK 128
#define EPC (NEDGES / NCHUNK)        // 25000 edges per chunk

// ---- bf16 helpers (RNE pack; unpack via shift) ----
__device__ __forceinline__ unsigned short f2bf(float x) {
    unsigned u = __float_as_uint(x);
    unsigned r = u + 0x7FFFu + ((u >> 16) & 1u);
    return (unsigned short)(r >> 16);
}
__device__ __forceinline__ void unpack8(uint4 v, float* f) {
    f[0] = __uint_as_float(v.x << 16); f[1] = __uint_as_float(v.x & 0xFFFF0000u);
    f[2] = __uint_as_float(v.y << 16); f[3] = __uint_as_float(v.y & 0xFFFF0000u);
    f[4] = __uint_as_float(v.z << 16); f[5] = __uint_as_float(v.z & 0xFFFF0000u);
    f[6] = __uint_as_float(v.w << 16); f[7] = __uint_as_float(v.w & 0xFFFF0000u);
}

// ---------------- init: zero small accumulators ----------------
__global__ void init_kernel(float* __restrict__ smalls) {
    int t = threadIdx.x;
    if (t < 592) smalls[t] = 0.0f;   // colsum(8) ata(64) ge(512) (+spare)
}

// ---------------- pass 1: per-chunk bucket histogram (LDS) ----------------
__global__ __launch_bounds__(1024) void chunk_hist_kernel(const int* __restrict__ dst,
                                                          int* __restrict__ hist) {
    __shared__ int h[NBUK];
    int c = blockIdx.x, t = threadIdx.x;
    for (int i = t; i < NBUK; i += 1024) h[i] = 0;
    __syncthreads();
    int e0 = c * EPC, e1 = e0 + EPC;
    for (int e = e0 + t; e < e1; e += 1024)
        atomicAdd(&h[dst[e] >> 7], 1);
    __syncthreads();
    for (int i = t; i < NBUK; i += 1024)
        hist[c * NBUK + i] = h[i];
}

// ---------------- pass 2: per-bucket exclusive prefix over chunks ----------------
__global__ void col_scan_kernel(int* __restrict__ hist, int* __restrict__ btot) {
    int t = blockIdx.x * 256 + threadIdx.x;
    if (t >= NBUK) return;
    int run = 0;
    for (int c = 0; c < NCHUNK; c++) {
        int idx = c * NBUK + t;
        int v = hist[idx];
        hist[idx] = run;
        run += v;
    }
    btot[t] = run;
}

// ---------------- pass 3: scan bucket totals -> bstart ----------------
__global__ void bucket_scan_kernel(const int* __restrict__ btot, int* __restrict__ bstart,
                                   int* __restrict__ row_start) {
    __shared__ int s[1024];
    int t = threadIdx.x;
    int v = (t < NBUK) ? btot[t] : 0;
    s[t] = v;
    __syncthreads();
    for (int off = 1; off < 1024; off <<= 1) {
        int x = (t >= off) ? s[t - off] : 0;
        __syncthreads();
        s[t] += x;
        __syncthreads();
    }
    if (t < NBUK) bstart[t] = s[t] - v;
    if (t == 0) {
        bstart[NBUK] = NEDGES;
        row_start[NNODES] = NEDGES;
    }
}

// ---------------- pass 4: deterministic scatter into bucket order (LDS cursors) ----------------
__global__ __launch_bounds__(1024) void chunk_scatter_kernel(const int* __restrict__ src,
                                                             const int* __restrict__ dst,
                                                             const int* __restrict__ hist,
                                                             const int* __restrict__ bstart,
                                                             int* __restrict__ ebuk) {
    __shared__ int cur[NBUK];
    int c = blockIdx.x, t = threadIdx.x;
    for (int i = t; i < NBUK; i += 1024)
        cur[i] = bstart[i] + hist[c * NBUK + i];
    __syncthreads();
    int e0 = c * EPC, e1 = e0 + EPC;
    for (int e = e0 + t; e < e1; e += 1024) {
        int d = dst[e];
        int pos = atomicAdd(&cur[d >> 7], 1);
        ebuk[pos] = src[e] | ((d & 127) << 20);   // src < 2^17 fits in 20 bits
    }
}

// ---------------- per-bucket: node counts, row_start, dinv, csr fill ----------------
__global__ __launch_bounds__(256) void build_kernel(const int* __restrict__ ebuk,
                                                    const int* __restrict__ bstart,
                                                    int* __restrict__ row_start,
                                                    float* __restrict__ dinv,
                                                    int* __restrict__ csr) {
    __shared__ int cnt[128];
    __shared__ int cur[128];
    int b = blockIdx.x;
    int t = threadIdx.x;
    int s0 = bstart[b], s1 = bstart[b + 1];
    if (t < 128) cnt[t] = 0;
    __syncthreads();
    for (int i = s0 + t; i < s1; i += 256)
        atomicAdd(&cnt[(ebuk[i] >> 20) & 127], 1);
    __syncthreads();
    if (t == 0) {
        int run = s0;
        for (int i = 0; i < 128; i++) { cur[i] = run; run += cnt[i]; }
    }
    __syncthreads();
    int node = b * 128 + t;
    if (t < 128 && node < NNODES) {
        row_start[node] = cur[t];
        dinv[node] = rsqrtf((float)cnt[t] + 1.0f);
    }
    __syncthreads();
    for (int i = s0 + t; i < s1; i += 256) {
        int v = ebuk[i];
        int pos = atomicAdd(&cur[(v >> 20) & 127], 1);
        csr[pos] = v & 0xFFFFF;
    }
}

// ---------------- register-tiled GEMM: stage(bf16) = rowscale * (A @ W) ----------------
// 256 threads; each thread computes R rows x 4 cols; A tile (TR x KIN) in padded LDS.
template <int KIN, int KOUT, int TR>
__global__ __launch_bounds__(256) void gemm_stage_kernel(const float* __restrict__ A,
                                                         const float* __restrict__ W,
                                                         const float* __restrict__ rowscale,
                                                         unsigned short* __restrict__ stage,
                                                         int nrows) {
    constexpr int COLG = KOUT / 4;        // col groups
    constexpr int ROWG = 256 / COLG;      // row groups
    constexpr int R    = TR / ROWG;       // rows per thread
    constexpr int LDK  = KIN + 4;         // pad: breaks 4-way bank aliasing
    __shared__ float As[TR][LDK];
    int block_row = blockIdx.x * TR;
    int tid = threadIdx.x;

    constexpr int C4 = KIN / 4;
    for (int idx = tid; idx < TR * C4; idx += 256) {
        int r = idx / C4, c = idx % C4;
        float4 v = make_float4(0.f, 0.f, 0.f, 0.f);
        if (block_row + r < nrows)
            v = *(const float4*)(A + (size_t)(block_row + r) * KIN + c * 4);
        *(float4*)(&As[r][c * 4]) = v;
    }
    __syncthreads();

    int cg = tid % COLG, rg = tid / COLG;
    int j  = cg * 4;
    int r0 = rg * R;
    float4 acc[R];
#pragma unroll
    for (int r = 0; r < R; r++) acc[r] = make_float4(0.f, 0.f, 0.f, 0.f);

#pragma unroll 4
    for (int k = 0; k < KIN; k++) {
        float4 w = *(const float4*)(W + (size_t)k * KOUT + j);
#pragma unroll
        for (int r = 0; r < R; r++) {
            float a = As[r0 + r][k];
            acc[r].x += a * w.x; acc[r].y += a * w.y;
            acc[r].z += a * w.z; acc[r].w += a * w.w;
        }
    }
#pragma unroll
    for (int r = 0; r < R; r++) {
        int row = block_row + r0 + r;
        if (row < nrows) {
            float d = rowscale[row];
            ushort4 p;
            p.x = f2bf(acc[r].x * d); p.y = f2bf(acc[r].y * d);
            p.z = f2bf(acc[r].z * d); p.w = f2bf(acc[r].w * d);
            *(ushort4*)(stage + (size_t)row * KOUT + j) = p;
        }
    }
}

// ---------------- gather K=128 bf16: one node/wave, 4 lane-quads, uint4(8 bf16)/lane ----------------
__global__ __launch_bounds__(256) void gather128_kernel(
    const unsigned short* __restrict__ hs, const int* __restrict__ row_start,
    const int* __restrict__ csr, const float* __restrict__ dinv,
    const float* __restrict__ bias, float* __restrict__ out) {
    int wave = threadIdx.x >> 6;
    int lane = threadIdx.x & 63;
    int n = blockIdx.x * 4 + wave;
    if (n >= NNODES) return;
    int q = lane >> 4;       // 0..3: edge sub-group
    int c = lane & 15;       // uint4 index within 256 B row
    const uint4* rows = (const uint4*)hs;    // row stride = 16 uint4
    int start = row_start[n], end = row_start[n + 1];
    float acc[8];
#pragma unroll
    for (int i = 0; i < 8; i++) acc[i] = 0.f;
    float f[8];
    int e = start + q;
    for (; e + 4 < end; e += 8) {
        uint4 v0 = rows[(size_t)csr[e] * 16 + c];
        uint4 v1 = rows[(size_t)csr[e + 4] * 16 + c];
        unpack8(v0, f);
#pragma unroll
        for (int i = 0; i < 8; i++) acc[i] += f[i];
        unpack8(v1, f);
#pragma unroll
        for (int i = 0; i < 8; i++) acc[i] += f[i];
    }
    for (; e < end; e += 4) {
        uint4 v = rows[(size_t)csr[e] * 16 + c];
        unpack8(v, f);
#pragma unroll
        for (int i = 0; i < 8; i++) acc[i] += f[i];
    }
#pragma unroll
    for (int off = 16; off <= 32; off <<= 1)
#pragma unroll
        for (int i = 0; i < 8; i++) acc[i] += __shfl_xor(acc[i], off);
    if (q == 0) {
        uint4 sv = rows[(size_t)n * 16 + c];
        unpack8(sv, f);
        float d = dinv[n];
        float4 b0 = ((const float4*)bias)[c * 2];
        float4 b1 = ((const float4*)bias)[c * 2 + 1];
        float4 r0, r1;
        r0.x = fmaxf((acc[0] + f[0]) * d + b0.x, 0.f);
        r0.y = fmaxf((acc[1] + f[1]) * d + b0.y, 0.f);
        r0.z = fmaxf((acc[2] + f[2]) * d + b0.z, 0.f);
        r0.w = fmaxf((acc[3] + f[3]) * d + b0.w, 0.f);
        r1.x = fmaxf((acc[4] + f[4]) * d + b1.x, 0.f);
        r1.y = fmaxf((acc[5] + f[5]) * d + b1.y, 0.f);
        r1.z = fmaxf((acc[6] + f[6]) * d + b1.z, 0.f);
        r1.w = fmaxf((acc[7] + f[7]) * d + b1.w, 0.f);
        float4* o = (float4*)(out + (size_t)n * 128 + c * 8);
        o[0] = r0; o[1] = r1;
    }
}

// ---------------- gather K=64 bf16: one node/wave, 8 lane-octets, uint4/lane ----------------
__global__ __launch_bounds__(256) void gather64_kernel(
    const unsigned short* __restrict__ hs, const int* __restrict__ row_start,
    const int* __restrict__ csr, const float* __restrict__ dinv,
    const float* __restrict__ bias, float* __restrict__ out) {
    int wave = threadIdx.x >> 6;
    int lane = threadIdx.x & 63;
    int n = blockIdx.x * 4 + wave;
    if (n >= NNODES) return;
    int g = lane >> 3;       // 0..7: edge sub-group
    int c = lane & 7;        // uint4 index within 128 B row
    const uint4* rows = (const uint4*)hs;    // row stride = 8 uint4
    int start = row_start[n], end = row_start[n + 1];
    float acc[8];
#pragma unroll
    for (int i = 0; i < 8; i++) acc[i] = 0.f;
    float f[8];
    int e = start + g;
    for (; e + 8 < end; e += 16) {
        uint4 v0 = rows[(size_t)csr[e] * 8 + c];
        uint4 v1 = rows[(size_t)csr[e + 8] * 8 + c];
        unpack8(v0, f);
#pragma unroll
        for (int i = 0; i < 8; i++) acc[i] += f[i];
        unpack8(v1, f);
#pragma unroll
        for (int i = 0; i < 8; i++) acc[i] += f[i];
    }
    for (; e < end; e += 8) {
        uint4 v = rows[(size_t)csr[e] * 8 + c];
        unpack8(v, f);
#pragma unroll
        for (int i = 0; i < 8; i++) acc[i] += f[i];
    }
#pragma unroll
    for (int off = 8; off <= 32; off <<= 1)
#pragma unroll
        for (int i = 0; i < 8; i++) acc[i] += __shfl_xor(acc[i], off);
    if (lane < 8) {
        uint4 sv = rows[(size_t)n * 8 + c];
        unpack8(sv, f);
        float d = dinv[n];
        float4 b0 = ((const float4*)bias)[c * 2];
        float4 b1 = ((const float4*)bias)[c * 2 + 1];
        float4 r0, r1;
        r0.x = (acc[0] + f[0]) * d + b0.x;
        r0.y = (acc[1] + f[1]) * d + b0.y;
        r0.z = (acc[2] + f[2]) * d + b0.z;
        r0.w = (acc[3] + f[3]) * d + b0.w;
        r1.x = (acc[4] + f[4]) * d + b1.x;
        r1.y = (acc[5] + f[5]) * d + b1.y;
        r1.z = (acc[6] + f[6]) * d + b1.z;
        r1.w = (acc[7] + f[7]) * d + b1.w;
        float4* o = (float4*)(out + (size_t)n * 64 + c * 8);
        o[0] = r0; o[1] = r1;
    }
}

// ---------------- fused attention head (64 rows/block, register-tiled phase 1) ----------------
// att = exp(tanh(h2@Wf1+bf1)@Wf2+bf2); per-block column sums into colsum.
__global__ __launch_bounds__(256) void attn_kernel(const float* __restrict__ h2,
                                                   const float* __restrict__ Wf1,
                                                   const float* __restrict__ bf1,
                                                   const float* __restrict__ Wf2,
                                                   const float* __restrict__ bf2,
                                                   float* __restrict__ att,
                                                   float* __restrict__ colsum) {
    __shared__ float h2S[64][68];
    __shared__ float a1S[64][68];
    __shared__ float colS[8][64];
    int t = threadIdx.x;
    int base = blockIdx.x * 64;
    // zero colS (pad rows never write)
    colS[t >> 6][t & 63] = 0.f;
    colS[(t >> 6) + 4][t & 63] = 0.f;
    // load h2 tile: 1024 float4
#pragma unroll
    for (int q = 0; q < 4; q++) {
        int idx = t + q * 256;
        int r = idx >> 4, c = (idx & 15) * 4;
        int row = base + r;
        float4 v = (row < NNODES) ? *(const float4*)(h2 + (size_t)row * 64 + c)
                                  : make_float4(0.f, 0.f, 0.f, 0.f);
        *(float4*)(&h2S[r][c]) = v;
    }
    __syncthreads();
    // phase 1: a1 = tanh(h2 @ Wf1 + bf1); 4 rows x 4 cols per thread
    {
        int cg = t & 15, rg = t >> 4;
        int j = cg * 4, r0 = rg * 4;
        float4 b4 = *(const float4*)(bf1 + j);
        float4 acc[4];
#pragma unroll
        for (int r = 0; r < 4; r++) acc[r] = b4;
#pragma unroll 4
        for (int k = 0; k < 64; k++) {
            float4 w = *(const float4*)(Wf1 + (size_t)k * 64 + j);
#pragma unroll
            for (int r = 0; r < 4; r++) {
                float a = h2S[r0 + r][k];
                acc[r].x += a * w.x; acc[r].y += a * w.y;
                acc[r].z += a * w.z; acc[r].w += a * w.w;
            }
        }
#pragma unroll
        for (int r = 0; r < 4; r++) {
            a1S[r0 + r][j]     = tanhf(acc[r].x);
            a1S[r0 + r][j + 1] = tanhf(acc[r].y);
            a1S[r0 + r][j + 2] = tanhf(acc[r].z);
            a1S[r0 + r][j + 3] = tanhf(acc[r].w);
        }
    }
    __syncthreads();
    // phase 2: att = exp(a1 @ Wf2 + bf2); 2 rows x 1 col per thread
    {
        int c = t & 7, r = t >> 3;   // r in 0..31
#pragma unroll
        for (int h = 0; h < 2; h++) {
            int rr = r + h * 32;
            float acc = bf2[c];
            for (int k = 0; k < 64; k++)
                acc += a1S[rr][k] * Wf2[(size_t)k * 8 + c];
            int row = base + rr;
            if (row < NNODES) {
                float ev = __expf(acc);
                att[(size_t)row * 8 + c] = ev;
                colS[c][rr] = ev;
            }
        }
    }
    __syncthreads();
    if (t < 8) {
        float s = 0.f;
#pragma unroll
        for (int r = 0; r < 64; r++) s += colS[t][r];
        atomicAdd(colsum + t, s);
    }
}

// ---------------- pooled reductions: ge[8][64] += attU.T@h2 ; ata[8][8] += attU.T@attU ----
__global__ __launch_bounds__(512) void pooled_kernel(const float* __restrict__ att,
                                                     const float* __restrict__ h2,
                                                     float* __restrict__ ge,
                                                     float* __restrict__ ata) {
    __shared__ float attS[64][8];
    __shared__ float h2S[64][64];
    int t = threadIdx.x;
    int d = t >> 6, j = t & 63;
    int de = t >> 3, ee = t & 7;
    float acc = 0.f, acc2 = 0.f;
    int ntiles = (NNODES + 63) / 64;
    for (int tile = blockIdx.x; tile < ntiles; tile += gridDim.x) {
        int base = tile * 64;
        {
            int i = t >> 3, c = t & 7;
            int row = base + i;
            attS[i][c] = (row < NNODES) ? att[(size_t)row * 8 + c] : 0.f;
        }
#pragma unroll
        for (int q = 0; q < 2; q++) {
            int idx = t + q * 512;
            int i = idx >> 4;
            int c = (idx & 15) * 4;
            int row = base + i;
            float4 v = (row < NNODES) ? *(const float4*)(h2 + (size_t)row * 64 + c)
                                      : make_float4(0.f, 0.f, 0.f, 0.f);
            *(float4*)(&h2S[i][c]) = v;
        }
        __syncthreads();
#pragma unroll 8
        for (int i = 0; i < 64; i++) acc += attS[i][d] * h2S[i][j];
        if (t < 64) {
#pragma unroll 8
            for (int i = 0; i < 64; i++) acc2 += attS[i][de] * attS[i][ee];
        }
        __syncthreads();
    }
    atomicAdd(ge + d * 64 + j, acc);
    if (t < 64) atomicAdd(ata + de * 8 + ee, acc2);
}

// ---------------- tiny epilogue ----------------
__global__ void final_kernel(const float* __restrict__ geacc, const float* __restrict__ ata,
                             const float* __restrict__ colsum, const float* __restrict__ Wl,
                             const float* __restrict__ bl, float* __restrict__ out) {
    __shared__ float geF[512];
    __shared__ float inv[8];
    __shared__ float logits[10];
    int t = threadIdx.x;
    if (t < 8) inv[t] = 1.0f / colsum[t];
    __syncthreads();
    for (int idx = t; idx < 512; idx += 64) {
        int d = idx >> 6;
        float v = geacc[idx] * inv[d];
        geF[idx] = v;
        out[idx] = v;                       // graph_embedding
    }
    __syncthreads();
    if (t == 0) {
        float pen = 0.f;
        for (int d = 0; d < 8; d++) {
            float s = 0.f;
            for (int e = 0; e < 8; e++) {
                float p = ata[d * 8 + e] * inv[d] * inv[e] - (d == e ? 1.0f : 0.0f);
                s += p * p;
            }
            pen += sqrtf(s);
        }
        out[512] = pen;                     // penalty
    }
    if (t < 10) {
        float acc = bl[t];
        for (int k = 0; k < 512; k++) acc += geF[k] * Wl[(size_t)k * 10 + t];
        logits[t] = acc;
    }
    __syncthreads();
    if (t == 0) {
        float m = -INFINITY;
        for (int l = 0; l < 10; l++) m = fmaxf(m, logits[l]);
        float s = 0.f;
        for (int l = 0; l < 10; l++) s += expf(logits[l] - m);
        float ls = logf(s);
        for (int l = 0; l < 10; l++) out[513 + l] = logits[l] - m - ls;  // log_softmax
    }
}

extern "C" void kernel_launch(void* const* d_in, const int* in_sizes, int n_in,
                              void* d_out, int out_size, void* d_ws, size_t ws_size,
                              hipStream_t stream) {
    const int* esrc = (const int*)d_in[0];
    const int* edst = esrc + NEDGES;
    const float* X   = (const float*)d_in[1];
    const float* W1  = (const float*)d_in[2];
    const float* b1  = (const float*)d_in[3];
    const float* W2  = (const float*)d_in[4];
    const float* b2  = (const float*)d_in[5];
    const float* Wf1 = (const float*)d_in[6];
    const float* bf1 = (const float*)d_in[7];
    const float* Wf2 = (const float*)d_in[8];
    const float* bf2 = (const float*)d_in[9];
    const float* Wl  = (const float*)d_in[10];
    const float* bl  = (const float*)d_in[11];
    float* out = (float*)d_out;

    // workspace layout
    float* ws     = (float*)d_ws;
    float* dinv   = ws;                               // N (padded to 100352)
    float* smalls = ws + 100352;                      // 1024
    float* colsum = smalls + 8;                       // 8
    float* ata    = smalls + 16;                      // 64
    float* geacc  = smalls + 80;                      // 512
    float* A = ws + 101376;                           // N*128 fp32 region
    float* B = A + (size_t)NNODES * 128;              // N*128 fp32 region
    int* row_start = (int*)(B + (size_t)NNODES * 128);// N+1 (padded 100352)
    int* btot      = row_start + 100352;              // NBUK (padded 1024)
    int* bstart    = btot + 1024;                     // NBUK+1 (padded 1024)
    int* csr       = bstart + 1024;                   // E
    int* ebuk      = (int*)A;                         // E temp (consumed before gemm1 writes A)
    int* hist      = (int*)B;                         // NCHUNK*NBUK temp (consumed before gather128 writes B)
    unsigned short* stage = (unsigned short*)A;       // bf16 staging (N*128 or N*64)
    float* h1  = B;                                   // N*128 fp32
    float* h2  = B;                                   // N*64 fp32 (overwrites h1)
    float* L   = A;                                   // N*8 fp32 (att, after staging consumed)

    // ---- CSR build + dinv (deterministic two-pass counting sort) ----
    init_kernel<<<1, 1024, 0, stream>>>(smalls);
    chunk_hist_kernel<<<NCHUNK, 1024, 0, stream>>>(edst, hist);
    col_scan_kernel<<<4, 256, 0, stream>>>(hist, btot);
    bucket_scan_kernel<<<1, 1024, 0, stream>>>(btot, bstart, row_start);
    chunk_scatter_kernel<<<NCHUNK, 1024, 0, stream>>>(esrc, edst, hist, bstart, ebuk);
    build_kernel<<<NBUK, 256, 0, stream>>>(ebuk, bstart, row_start, dinv, csr);

    // ---- GCN layer 1: stage = bf16(dinv*(X@W1)); h1 = relu(gather(stage)*dinv + b1) ----
    gemm_stage_kernel<128, 128, 64><<<(NNODES + 63) / 64, 256, 0, stream>>>(X, W1, dinv, stage, NNODES);
    gather128_kernel<<<(NNODES + 3) / 4, 256, 0, stream>>>(stage, row_start, csr, dinv, b1, h1);

    // ---- GCN layer 2: stage = bf16(dinv*(h1@W2)); h2 = gather(stage)*dinv + b2 ----
    gemm_stage_kernel<128, 64, 64><<<(NNODES + 63) / 64, 256, 0, stream>>>(h1, W2, dinv, stage, NNODES);
    gather64_kernel<<<(NNODES + 3) / 4, 256, 0, stream>>>(stage, row_start, csr, dinv, b2, h2);

    // ---- fused attention head: att(L) = exp(tanh(h2@Wf1+bf1)@Wf2+bf2), colsum ----
    attn_kernel<<<(NNODES + 63) / 64, 256, 0, stream>>>(h2, Wf1, bf1, Wf2, bf2, L, colsum);

    // ---- pooling + epilogue ----
    pooled_kernel<<<512, 512, 0, stream>>>(L, h2, geacc, ata);
    final_kernel<<<1, 64, 0, stream>>>(geacc, ata, colsum, Wl, bl, out);
}

// Round 7
// 509.113 us; speedup vs baseline: 3.6153x; 1.0891x over previous
//
#include <hip/hip_runtime.h>
#include <hip/hip_bf16.h>
#include <math.h>

#define NNODES 100000
#define NEDGES 3200000
#define NBUK ((NNODES + 127) >> 7)   // 782 buckets of 128 nodes
#define NCHUNK 128
#define EPC (NEDGES / NCHUNK)        // 25000 edges per chunk

typedef float floatx2 __attribute__((ext_vector_type(2)));

// ---- fp8 e4m3 helpers (gfx950 HW converts, OCP e4m3fn) ----
__device__ __forceinline__ void unpack16_fp8(uint4 v, float* f) {
    floatx2 p;
    p = __builtin_amdgcn_cvt_pk_f32_fp8(v.x, false); f[0] = p.x; f[1] = p.y;
    p = __builtin_amdgcn_cvt_pk_f32_fp8(v.x, true);  f[2] = p.x; f[3] = p.y;
    p = __builtin_amdgcn_cvt_pk_f32_fp8(v.y, false); f[4] = p.x; f[5] = p.y;
    p = __builtin_amdgcn_cvt_pk_f32_fp8(v.y, true);  f[6] = p.x; f[7] = p.y;
    p = __builtin_amdgcn_cvt_pk_f32_fp8(v.z, false); f[8] = p.x; f[9] = p.y;
    p = __builtin_amdgcn_cvt_pk_f32_fp8(v.z, true);  f[10] = p.x; f[11] = p.y;
    p = __builtin_amdgcn_cvt_pk_f32_fp8(v.w, false); f[12] = p.x; f[13] = p.y;
    p = __builtin_amdgcn_cvt_pk_f32_fp8(v.w, true);  f[14] = p.x; f[15] = p.y;
}
__device__ __forceinline__ void unpack8_fp8(uint2 v, float* f) {
    floatx2 p;
    p = __builtin_amdgcn_cvt_pk_f32_fp8(v.x, false); f[0] = p.x; f[1] = p.y;
    p = __builtin_amdgcn_cvt_pk_f32_fp8(v.x, true);  f[2] = p.x; f[3] = p.y;
    p = __builtin_amdgcn_cvt_pk_f32_fp8(v.y, false); f[4] = p.x; f[5] = p.y;
    p = __builtin_amdgcn_cvt_pk_f32_fp8(v.y, true);  f[6] = p.x; f[7] = p.y;
}

// ---------------- pass 1: per-chunk bucket histogram (LDS) ----------------
__global__ __launch_bounds__(1024) void chunk_hist_kernel(const int* __restrict__ dst,
                                                          int* __restrict__ hist) {
    __shared__ int h[NBUK];
    int c = blockIdx.x, t = threadIdx.x;
    for (int i = t; i < NBUK; i += 1024) h[i] = 0;
    __syncthreads();
    int e0 = c * EPC, e1 = e0 + EPC;
    for (int e = e0 + t; e < e1; e += 1024)
        atomicAdd(&h[dst[e] >> 7], 1);
    __syncthreads();
    for (int i = t; i < NBUK; i += 1024)
        hist[c * NBUK + i] = h[i];
}

// ---------------- pass 2: per-bucket exclusive prefix over chunks ----------------
__global__ void col_scan_kernel(int* __restrict__ hist, int* __restrict__ btot) {
    int t = blockIdx.x * 256 + threadIdx.x;
    if (t >= NBUK) return;
    int run = 0;
    for (int c = 0; c < NCHUNK; c++) {
        int idx = c * NBUK + t;
        int v = hist[idx];
        hist[idx] = run;
        run += v;
    }
    btot[t] = run;
}

// ---------------- pass 3: scan bucket totals -> bstart; zero small accumulators ----------------
__global__ void bucket_scan_kernel(const int* __restrict__ btot, int* __restrict__ bstart,
                                   int* __restrict__ row_start, float* __restrict__ smalls) {
    __shared__ int s[1024];
    int t = threadIdx.x;
    if (t < 592) smalls[t] = 0.0f;   // colsum(8) ata(64) ge(512)
    int v = (t < NBUK) ? btot[t] : 0;
    s[t] = v;
    __syncthreads();
    for (int off = 1; off < 1024; off <<= 1) {
        int x = (t >= off) ? s[t - off] : 0;
        __syncthreads();
        s[t] += x;
        __syncthreads();
    }
    if (t < NBUK) bstart[t] = s[t] - v;
    if (t == 0) {
        bstart[NBUK] = NEDGES;
        row_start[NNODES] = NEDGES;
    }
}

// ---------------- pass 4: deterministic scatter into bucket order (LDS cursors) ----------------
__global__ __launch_bounds__(1024) void chunk_scatter_kernel(const int* __restrict__ src,
                                                             const int* __restrict__ dst,
                                                             const int* __restrict__ hist,
                                                             const int* __restrict__ bstart,
                                                             int* __restrict__ ebuk) {
    __shared__ int cur[NBUK];
    int c = blockIdx.x, t = threadIdx.x;
    for (int i = t; i < NBUK; i += 1024)
        cur[i] = bstart[i] + hist[c * NBUK + i];
    __syncthreads();
    int e0 = c * EPC, e1 = e0 + EPC;
    for (int e = e0 + t; e < e1; e += 1024) {
        int d = dst[e];
        int pos = atomicAdd(&cur[d >> 7], 1);
        ebuk[pos] = src[e] | ((d & 127) << 20);   // src < 2^17 fits in 20 bits
    }
}

// ---------------- per-bucket: node counts, row_start, dinv, csr fill ----------------
__global__ __launch_bounds__(256) void build_kernel(const int* __restrict__ ebuk,
                                                    const int* __restrict__ bstart,
                                                    int* __restrict__ row_start,
                                                    float* __restrict__ dinv,
                                                    int* __restrict__ csr) {
    __shared__ int cnt[128];
    __shared__ int cur[128];
    int b = blockIdx.x;
    int t = threadIdx.x;
    int s0 = bstart[b], s1 = bstart[b + 1];
    if (t < 128) cnt[t] = 0;
    __syncthreads();
    for (int i = s0 + t; i < s1; i += 256)
        atomicAdd(&cnt[(ebuk[i] >> 20) & 127], 1);
    __syncthreads();
    if (t == 0) {
        int run = s0;
        for (int i = 0; i < 128; i++) { cur[i] = run; run += cnt[i]; }
    }
    __syncthreads();
    int node = b * 128 + t;
    if (t < 128 && node < NNODES) {
        row_start[node] = cur[t];
        dinv[node] = rsqrtf((float)cnt[t] + 1.0f);
    }
    __syncthreads();
    for (int i = s0 + t; i < s1; i += 256) {
        int v = ebuk[i];
        int pos = atomicAdd(&cur[(v >> 20) & 127], 1);
        csr[pos] = v & 0xFFFFF;
    }
}

// ---------------- register-tiled GEMM: stage(fp8 e4m3) = rowscale * (A @ W) ----------------
template <int KIN, int KOUT, int TR>
__global__ __launch_bounds__(256) void gemm_stage_kernel(const float* __restrict__ A,
                                                         const float* __restrict__ W,
                                                         const float* __restrict__ rowscale,
                                                         unsigned char* __restrict__ stage,
                                                         int nrows) {
    constexpr int COLG = KOUT / 4;
    constexpr int ROWG = 256 / COLG;
    constexpr int R    = TR / ROWG;
    constexpr int LDK  = KIN + 4;
    __shared__ float As[TR][LDK];
    int block_row = blockIdx.x * TR;
    int tid = threadIdx.x;

    constexpr int C4 = KIN / 4;
    for (int idx = tid; idx < TR * C4; idx += 256) {
        int r = idx / C4, c = idx % C4;
        float4 v = make_float4(0.f, 0.f, 0.f, 0.f);
        if (block_row + r < nrows)
            v = *(const float4*)(A + (size_t)(block_row + r) * KIN + c * 4);
        *(float4*)(&As[r][c * 4]) = v;
    }
    __syncthreads();

    int cg = tid % COLG, rg = tid / COLG;
    int j  = cg * 4;
    int r0 = rg * R;
    float4 acc[R];
#pragma unroll
    for (int r = 0; r < R; r++) acc[r] = make_float4(0.f, 0.f, 0.f, 0.f);

#pragma unroll 4
    for (int k = 0; k < KIN; k++) {
        float4 w = *(const float4*)(W + (size_t)k * KOUT + j);
#pragma unroll
        for (int r = 0; r < R; r++) {
            float a = As[r0 + r][k];
            acc[r].x += a * w.x; acc[r].y += a * w.y;
            acc[r].z += a * w.z; acc[r].w += a * w.w;
        }
    }
#pragma unroll
    for (int r = 0; r < R; r++) {
        int row = block_row + r0 + r;
        if (row < nrows) {
            float d = rowscale[row];
            int pk = __builtin_amdgcn_cvt_pk_fp8_f32(acc[r].x * d, acc[r].y * d, 0, false);
            pk = __builtin_amdgcn_cvt_pk_fp8_f32(acc[r].z * d, acc[r].w * d, pk, true);
            *(unsigned*)(stage + (size_t)row * KOUT + j) = (unsigned)pk;
        }
    }
}

// ---------------- gather K=128 fp8: one node/wave, 8 lane-octets, uint4(16 fp8)/lane ----------------
__global__ __launch_bounds__(256) void gather128_kernel(
    const unsigned char* __restrict__ hs, const int* __restrict__ row_start,
    const int* __restrict__ csr, const float* __restrict__ dinv,
    const float* __restrict__ bias, float* __restrict__ out) {
    int wave = threadIdx.x >> 6;
    int lane = threadIdx.x & 63;
    int n = blockIdx.x * 4 + wave;
    if (n >= NNODES) return;
    int g = lane >> 3;       // 0..7: edge sub-group
    int c = lane & 7;        // uint4 index within 128 B row
    const uint4* rows = (const uint4*)hs;    // row stride = 8 uint4
    int start = row_start[n], end = row_start[n + 1];
    float acc[16];
#pragma unroll
    for (int i = 0; i < 16; i++) acc[i] = 0.f;
    float f[16];
    int e = start + g;
    for (; e + 8 < end; e += 16) {
        uint4 v0 = rows[(size_t)csr[e] * 8 + c];
        uint4 v1 = rows[(size_t)csr[e + 8] * 8 + c];
        unpack16_fp8(v0, f);
#pragma unroll
        for (int i = 0; i < 16; i++) acc[i] += f[i];
        unpack16_fp8(v1, f);
#pragma unroll
        for (int i = 0; i < 16; i++) acc[i] += f[i];
    }
    for (; e < end; e += 8) {
        uint4 v = rows[(size_t)csr[e] * 8 + c];
        unpack16_fp8(v, f);
#pragma unroll
        for (int i = 0; i < 16; i++) acc[i] += f[i];
    }
#pragma unroll
    for (int off = 8; off <= 32; off <<= 1)
#pragma unroll
        for (int i = 0; i < 16; i++) acc[i] += __shfl_xor(acc[i], off);
    if (lane < 8) {
        uint4 sv = rows[(size_t)n * 8 + c];
        unpack16_fp8(sv, f);
        float d = dinv[n];
        float* o = out + (size_t)n * 128 + c * 16;
        const float* bi = bias + c * 16;
#pragma unroll
        for (int h = 0; h < 4; h++) {
            float4 b4 = *(const float4*)(bi + h * 4);
            float4 r;
            r.x = fmaxf((acc[h * 4 + 0] + f[h * 4 + 0]) * d + b4.x, 0.f);
            r.y = fmaxf((acc[h * 4 + 1] + f[h * 4 + 1]) * d + b4.y, 0.f);
            r.z = fmaxf((acc[h * 4 + 2] + f[h * 4 + 2]) * d + b4.z, 0.f);
            r.w = fmaxf((acc[h * 4 + 3] + f[h * 4 + 3]) * d + b4.w, 0.f);
            *(float4*)(o + h * 4) = r;
        }
    }
}

// ---------------- gather K=64 fp8: one node/wave, 8 lane-octets, uint2(8 fp8)/lane ----------------
__global__ __launch_bounds__(256) void gather64_kernel(
    const unsigned char* __restrict__ hs, const int* __restrict__ row_start,
    const int* __restrict__ csr, const float* __restrict__ dinv,
    const float* __restrict__ bias, float* __restrict__ out) {
    int wave = threadIdx.x >> 6;
    int lane = threadIdx.x & 63;
    int n = blockIdx.x * 4 + wave;
    if (n >= NNODES) return;
    int g = lane >> 3;       // 0..7: edge sub-group
    int c = lane & 7;        // uint2 index within 64 B row
    const uint2* rows = (const uint2*)hs;    // row stride = 8 uint2
    int start = row_start[n], end = row_start[n + 1];
    float acc[8];
#pragma unroll
    for (int i = 0; i < 8; i++) acc[i] = 0.f;
    float f[8];
    int e = start + g;
    for (; e + 8 < end; e += 16) {
        uint2 v0 = rows[(size_t)csr[e] * 8 + c];
        uint2 v1 = rows[(size_t)csr[e + 8] * 8 + c];
        unpack8_fp8(v0, f);
#pragma unroll
        for (int i = 0; i < 8; i++) acc[i] += f[i];
        unpack8_fp8(v1, f);
#pragma unroll
        for (int i = 0; i < 8; i++) acc[i] += f[i];
    }
    for (; e < end; e += 8) {
        uint2 v = rows[(size_t)csr[e] * 8 + c];
        unpack8_fp8(v, f);
#pragma unroll
        for (int i = 0; i < 8; i++) acc[i] += f[i];
    }
#pragma unroll
    for (int off = 8; off <= 32; off <<= 1)
#pragma unroll
        for (int i = 0; i < 8; i++) acc[i] += __shfl_xor(acc[i], off);
    if (lane < 8) {
        uint2 sv = rows[(size_t)n * 8 + c];
        unpack8_fp8(sv, f);
        float d = dinv[n];
        float4 b0 = ((const float4*)bias)[c * 2];
        float4 b1 = ((const float4*)bias)[c * 2 + 1];
        float4 r0, r1;
        r0.x = (acc[0] + f[0]) * d + b0.x;
        r0.y = (acc[1] + f[1]) * d + b0.y;
        r0.z = (acc[2] + f[2]) * d + b0.z;
        r0.w = (acc[3] + f[3]) * d + b0.w;
        r1.x = (acc[4] + f[4]) * d + b1.x;
        r1.y = (acc[5] + f[5]) * d + b1.y;
        r1.z = (acc[6] + f[6]) * d + b1.z;
        r1.w = (acc[7] + f[7]) * d + b1.w;
        float4* o = (float4*)(out + (size_t)n * 64 + c * 8);
        o[0] = r0; o[1] = r1;
    }
}

// ---------------- fused attention head (64 rows/block, register-tiled phase 1) ----------------
__global__ __launch_bounds__(256) void attn_kernel(const float* __restrict__ h2,
                                                   const float* __restrict__ Wf1,
                                                   const float* __restrict__ bf1,
                                                   const float* __restrict__ Wf2,
                                                   const float* __restrict__ bf2,
                                                   float* __restrict__ att,
                                                   float* __restrict__ colsum) {
    __shared__ float h2S[64][68];
    __shared__ float a1S[64][68];
    __shared__ float colS[8][64];
    int t = threadIdx.x;
    int base = blockIdx.x * 64;
    colS[t >> 6][t & 63] = 0.f;
    colS[(t >> 6) + 4][t & 63] = 0.f;
#pragma unroll
    for (int q = 0; q < 4; q++) {
        int idx = t + q * 256;
        int r = idx >> 4, c = (idx & 15) * 4;
        int row = base + r;
        float4 v = (row < NNODES) ? *(const float4*)(h2 + (size_t)row * 64 + c)
                                  : make_float4(0.f, 0.f, 0.f, 0.f);
        *(float4*)(&h2S[r][c]) = v;
    }
    __syncthreads();
    {
        int cg = t & 15, rg = t >> 4;
        int j = cg * 4, r0 = rg * 4;
        float4 b4 = *(const float4*)(bf1 + j);
        float4 acc[4];
#pragma unroll
        for (int r = 0; r < 4; r++) acc[r] = b4;
#pragma unroll 4
        for (int k = 0; k < 64; k++) {
            float4 w = *(const float4*)(Wf1 + (size_t)k * 64 + j);
#pragma unroll
            for (int r = 0; r < 4; r++) {
                float a = h2S[r0 + r][k];
                acc[r].x += a * w.x; acc[r].y += a * w.y;
                acc[r].z += a * w.z; acc[r].w += a * w.w;
            }
        }
#pragma unroll
        for (int r = 0; r < 4; r++) {
            a1S[r0 + r][j]     = tanhf(acc[r].x);
            a1S[r0 + r][j + 1] = tanhf(acc[r].y);
            a1S[r0 + r][j + 2] = tanhf(acc[r].z);
            a1S[r0 + r][j + 3] = tanhf(acc[r].w);
        }
    }
    __syncthreads();
    {
        int c = t & 7, r = t >> 3;   // r in 0..31
#pragma unroll
        for (int h = 0; h < 2; h++) {
            int rr = r + h * 32;
            float acc = bf2[c];
            for (int k = 0; k < 64; k++)
                acc += a1S[rr][k] * Wf2[(size_t)k * 8 + c];
            int row = base + rr;
            if (row < NNODES) {
                float ev = __expf(acc);
                att[(size_t)row * 8 + c] = ev;
                colS[c][rr] = ev;
            }
        }
    }
    __syncthreads();
    if (t < 8) {
        float s = 0.f;
#pragma unroll
        for (int r = 0; r < 64; r++) s += colS[t][r];
        atomicAdd(colsum + t, s);
    }
}

// ---------------- pooled reductions: ge[8][64] += attU.T@h2 ; ata[8][8] += attU.T@attU ----
__global__ __launch_bounds__(512) void pooled_kernel(const float* __restrict__ att,
                                                     const float* __restrict__ h2,
                                                     float* __restrict__ ge,
                                                     float* __restrict__ ata) {
    __shared__ float attS[64][8];
    __shared__ float h2S[64][64];
    int t = threadIdx.x;
    int d = t >> 6, j = t & 63;
    int de = t >> 3, ee = t & 7;
    float acc = 0.f, acc2 = 0.f;
    int ntiles = (NNODES + 63) / 64;
    for (int tile = blockIdx.x; tile < ntiles; tile += gridDim.x) {
        int base = tile * 64;
        {
            int i = t >> 3, c = t & 7;
            int row = base + i;
            attS[i][c] = (row < NNODES) ? att[(size_t)row * 8 + c] : 0.f;
        }
#pragma unroll
        for (int q = 0; q < 2; q++) {
            int idx = t + q * 512;
            int i = idx >> 4;
            int c = (idx & 15) * 4;
            int row = base + i;
            float4 v = (row < NNODES) ? *(const float4*)(h2 + (size_t)row * 64 + c)
                                      : make_float4(0.f, 0.f, 0.f, 0.f);
            *(float4*)(&h2S[i][c]) = v;
        }
        __syncthreads();
#pragma unroll 8
        for (int i = 0; i < 64; i++) acc += attS[i][d] * h2S[i][j];
        if (t < 64) {
#pragma unroll 8
            for (int i = 0; i < 64; i++) acc2 += attS[i][de] * attS[i][ee];
        }
        __syncthreads();
    }
    atomicAdd(ge + d * 64 + j, acc);
    if (t < 64) atomicAdd(ata + de * 8 + ee, acc2);
}

// ---------------- tiny epilogue ----------------
__global__ void final_kernel(const float* __restrict__ geacc, const float* __restrict__ ata,
                             const float* __restrict__ colsum, const float* __restrict__ Wl,
                             const float* __restrict__ bl, float* __restrict__ out) {
    __shared__ float geF[512];
    __shared__ float inv[8];
    __shared__ float logits[10];
    int t = threadIdx.x;
    if (t < 8) inv[t] = 1.0f / colsum[t];
    __syncthreads();
    for (int idx = t; idx < 512; idx += 64) {
        int d = idx >> 6;
        float v = geacc[idx] * inv[d];
        geF[idx] = v;
        out[idx] = v;                       // graph_embedding
    }
    __syncthreads();
    if (t == 0) {
        float pen = 0.f;
        for (int d = 0; d < 8; d++) {
            float s = 0.f;
            for (int e = 0; e < 8; e++) {
                float p = ata[d * 8 + e] * inv[d] * inv[e] - (d == e ? 1.0f : 0.0f);
                s += p * p;
            }
            pen += sqrtf(s);
        }
        out[512] = pen;                     // penalty
    }
    if (t < 10) {
        float acc = bl[t];
        for (int k = 0; k < 512; k++) acc += geF[k] * Wl[(size_t)k * 10 + t];
        logits[t] = acc;
    }
    __syncthreads();
    if (t == 0) {
        float m = -INFINITY;
        for (int l = 0; l < 10; l++) m = fmaxf(m, logits[l]);
        float s = 0.f;
        for (int l = 0; l < 10; l++) s += expf(logits[l] - m);
        float ls = logf(s);
        for (int l = 0; l < 10; l++) out[513 + l] = logits[l] - m - ls;  // log_softmax
    }
}

extern "C" void kernel_launch(void* const* d_in, const int* in_sizes, int n_in,
                              void* d_out, int out_size, void* d_ws, size_t ws_size,
                              hipStream_t stream) {
    const int* esrc = (const int*)d_in[0];
    const int* edst = esrc + NEDGES;
    const float* X   = (const float*)d_in[1];
    const float* W1  = (const float*)d_in[2];
    const float* b1  = (const float*)d_in[3];
    const float* W2  = (const float*)d_in[4];
    const float* b2  = (const float*)d_in[5];
    const float* Wf1 = (const float*)d_in[6];
    const float* bf1 = (const float*)d_in[7];
    const float* Wf2 = (const float*)d_in[8];
    const float* bf2 = (const float*)d_in[9];
    const float* Wl  = (const float*)d_in[10];
    const float* bl  = (const float*)d_in[11];
    float* out = (float*)d_out;

    // workspace layout
    float* ws     = (float*)d_ws;
    float* dinv   = ws;                               // N (padded to 100352)
    float* smalls = ws + 100352;                      // 1024
    float* colsum = smalls + 8;                       // 8
    float* ata    = smalls + 16;                      // 64
    float* geacc  = smalls + 80;                      // 512
    float* A = ws + 101376;                           // N*128 fp32 region
    float* B = A + (size_t)NNODES * 128;              // N*128 fp32 region
    int* row_start = (int*)(B + (size_t)NNODES * 128);// N+1 (padded 100352)
    int* btot      = row_start + 100352;              // NBUK (padded 1024)
    int* bstart    = btot + 1024;                     // NBUK+1 (padded 1024)
    int* csr       = bstart + 1024;                   // E
    int* ebuk      = (int*)A;                         // E temp (consumed before gemm1 writes A)
    int* hist      = (int*)B;                         // NCHUNK*NBUK temp (consumed before gather128 writes B)
    unsigned char* stage = (unsigned char*)A;         // fp8 staging (N*128 or N*64 bytes)
    float* h1  = B;                                   // N*128 fp32
    float* h2  = B;                                   // N*64 fp32 (overwrites h1)
    float* L   = A;                                   // N*8 fp32 (att, after staging consumed)

    // ---- CSR build + dinv (deterministic two-pass counting sort) ----
    chunk_hist_kernel<<<NCHUNK, 1024, 0, stream>>>(edst, hist);
    col_scan_kernel<<<4, 256, 0, stream>>>(hist, btot);
    bucket_scan_kernel<<<1, 1024, 0, stream>>>(btot, bstart, row_start, smalls);
    chunk_scatter_kernel<<<NCHUNK, 1024, 0, stream>>>(esrc, edst, hist, bstart, ebuk);
    build_kernel<<<NBUK, 256, 0, stream>>>(ebuk, bstart, row_start, dinv, csr);

    // ---- GCN layer 1: stage = fp8(dinv*(X@W1)); h1 = relu(gather(stage)*dinv + b1) ----
    gemm_stage_kernel<128, 128, 64><<<(NNODES + 63) / 64, 256, 0, stream>>>(X, W1, dinv, stage, NNODES);
    gather128_kernel<<<(NNODES + 3) / 4, 256, 0, stream>>>(stage, row_start, csr, dinv, b1, h1);

    // ---- GCN layer 2: stage = fp8(dinv*(h1@W2)); h2 = gather(stage)*dinv + b2 ----
    gemm_stage_kernel<128, 64, 64><<<(NNODES + 63) / 64, 256, 0, stream>>>(h1, W2, dinv, stage, NNODES);
    gather64_kernel<<<(NNODES + 3) / 4, 256, 0, stream>>>(stage, row_start, csr, dinv, b2, h2);

    // ---- fused attention head: att(L) = exp(tanh(h2@Wf1+bf1)@Wf2+bf2), colsum ----
    attn_kernel<<<(NNODES + 63) / 64, 256, 0, stream>>>(h2, Wf1, bf1, Wf2, bf2, L, colsum);

    // ---- pooling + epilogue ----
    pooled_kernel<<<512, 512, 0, stream>>>(L, h2, geacc, ata);
    final_kernel<<<1, 64, 0, stream>>>(geacc, ata, colsum, Wl, bl, out);
}